// Round 1
// baseline (540.357 us; speedup 1.0000x reference)
//
#include <hip/hip_runtime.h>
#include <math.h>

#define NH   8
#define HD   32
#define NP   4
#define EMB  256
#define IMG_H 100
#define IMG_W 100
#define NQ   10000
#define NV   10000
#define BS   4

#define WS 36   // LDS row stride for 32-wide weight rows (16B aligned, 4-way worst conflict)
#define QS 36   // LDS row stride for per-head 32-float vectors

// ---------------- Kernel 1: precompute K = Wk * grid_sample(key, grids[:, :1]) + bk ----
// grid: 32 blocks (b*8+h), 64 threads. Output kk[b][p][h][dout], 4*4*8*32 floats.
__global__ __launch_bounds__(64) void k1_keys(
    const float* __restrict__ query, const float* __restrict__ key,
    const float* __restrict__ refp,  const float* __restrict__ Woff,
    const float* __restrict__ boff,  const float* __restrict__ Wk,
    const float* __restrict__ bk,    float* __restrict__ kk)
{
    int b = blockIdx.x >> 3, h = blockIdx.x & 7;
    __shared__ float q0[HD];
    __shared__ float off[8];
    __shared__ float ks[NP][HD];
    int l = threadIdx.x;

    if (l < HD) q0[l] = query[(size_t)(b * NQ) * EMB + h * HD + l];
    __syncthreads();

    if (l < 8) {
        float s = boff[l];
        #pragma unroll
        for (int d = 0; d < HD; ++d) s += q0[d] * Woff[l * HD + d];
        off[l] = s;
    }
    __syncthreads();

    if (l < HD) {
        float refx = refp[(size_t)(b * NQ) * 2 + 0];
        float refy = refp[(size_t)(b * NQ) * 2 + 1];
        for (int p = 0; p < NP; ++p) {
            float x = refx * IMG_W + off[p * 2 + 0] - 0.5f;
            float y = refy * IMG_H + off[p * 2 + 1] - 0.5f;
            float x0f = floorf(x), y0f = floorf(y);
            int ix0 = (int)x0f, iy0 = (int)y0f;
            float fx = x - x0f, fy = y - y0f;
            float acc = 0.f;
            #pragma unroll
            for (int cy = 0; cy < 2; ++cy) {
                #pragma unroll
                for (int cx = 0; cx < 2; ++cx) {
                    int xi = ix0 + cx, yi = iy0 + cy;
                    if ((unsigned)xi < IMG_W && (unsigned)yi < IMG_H) {
                        float wgt = (cx ? fx : 1.f - fx) * (cy ? fy : 1.f - fy);
                        acc += wgt * key[((size_t)b * NV + yi * IMG_W + xi) * EMB + h * HD + l];
                    }
                }
            }
            ks[p][l] = acc;
        }
    }
    __syncthreads();

    for (int t = 0; t < 2; ++t) {
        int idx = l + 64 * t;           // 0..127 -> (p, dout)
        int p = idx >> 5, dout = idx & 31;
        float s = bk[dout];
        #pragma unroll
        for (int d = 0; d < HD; ++d) s += Wk[dout * HD + d] * ks[p][d];
        kk[((b * NP + p) * NH + h) * HD + dout] = s;
    }
}

// ---------------- Kernel 2: per-query pipeline, one wave per query ------------------
// grid: BS*NQ/4 blocks, 256 threads (4 waves, 1 query each).
__global__ __launch_bounds__(256) void k2_main(
    const float* __restrict__ query, const float* __restrict__ value,
    const float* __restrict__ refp,
    const float* __restrict__ Wq, const float* __restrict__ bq,
    const float* __restrict__ Wv, const float* __restrict__ bv,
    const float* __restrict__ Woff, const float* __restrict__ boff,
    const float* __restrict__ kk, float* __restrict__ pre)
{
    __shared__ float sWq[HD * WS];
    __shared__ float sWv[HD * WS];
    __shared__ float sWoff[8 * WS];
    __shared__ float sbq[HD], sbv[HD], sboff[8];
    __shared__ float qld[4][NH * QS];
    __shared__ float qproj[4][NH * QS];
    __shared__ float offs[4][64];
    __shared__ float attnw[4][32];
    __shared__ int   six0[4][32], siy0[4][32];
    __shared__ float sfx[4][32], sfy[4][32];
    __shared__ float vs[4][32 * HD];     // [hp][d]
    __shared__ float agg[4][NH * QS];

    int tid = threadIdx.x;
    // stage weights once per block
    for (int i = tid; i < HD * HD; i += 256) sWq[(i >> 5) * WS + (i & 31)] = Wq[i];
    for (int i = tid; i < HD * HD; i += 256) sWv[(i >> 5) * WS + (i & 31)] = Wv[i];
    for (int i = tid; i < 8 * HD; i += 256)  sWoff[(i >> 5) * WS + (i & 31)] = Woff[i];
    if (tid < HD) { sbq[tid] = bq[tid]; sbv[tid] = bv[tid]; }
    if (tid < 8)  sboff[tid] = boff[tid];

    int w = tid >> 6, lane = tid & 63;
    int gq = blockIdx.x * 4 + w;               // 0..BS*NQ-1, grid exact
    int b = gq / NQ, q = gq - b * NQ; (void)q;

    // phase 1: load query row (also the residual source, re-read in k3)
    float4 qv = *(const float4*)(query + (size_t)gq * EMB + lane * 4);
    {
        int e = lane * 4;
        *(float4*)&qld[w][(e >> 5) * QS + (e & 31)] = qv;
    }
    __syncthreads();

    // phase 2: qproj[h][dd] = bq + qld[h] . Wq[dd]
    #pragma unroll
    for (int i = 0; i < 4; ++i) {
        int o = i * 64 + lane;
        int h = o >> 5, dd = o & 31;
        float s = sbq[dd];
        const float* qr = &qld[w][h * QS];
        const float* wr = &sWq[dd * WS];
        #pragma unroll
        for (int d = 0; d < HD; d += 4) {
            float4 a = *(const float4*)(qr + d);
            float4 ww = *(const float4*)(wr + d);
            s += a.x * ww.x + a.y * ww.y + a.z * ww.z + a.w * ww.w;
        }
        qproj[w][h * QS + dd] = s;
    }
    // phase 3: sampling offsets, one (h,j) per lane
    {
        int h = lane >> 3, j = lane & 7;
        float s = sboff[j];
        const float* qr = &qld[w][h * QS];
        const float* wr = &sWoff[j * WS];
        #pragma unroll
        for (int d = 0; d < HD; d += 4) {
            float4 a = *(const float4*)(qr + d);
            float4 ww = *(const float4*)(wr + d);
            s += a.x * ww.x + a.y * ww.y + a.z * ww.z + a.w * ww.w;
        }
        offs[w][lane] = s;
    }
    __syncthreads();

    // phase 4: lanes<32: per-(h,p) sampling setup + logits + softmax over p
    float refx = refp[(size_t)gq * 2 + 0];
    float refy = refp[(size_t)gq * 2 + 1];
    if (lane < 32) {
        int h = lane >> 2, p = lane & 3;
        float x = refx * IMG_W + offs[w][h * 8 + p * 2 + 0] - 0.5f;
        float y = refy * IMG_H + offs[w][h * 8 + p * 2 + 1] - 0.5f;
        float x0f = floorf(x), y0f = floorf(y);
        six0[w][lane] = (int)x0f; siy0[w][lane] = (int)y0f;
        sfx[w][lane] = x - x0f;  sfy[w][lane] = y - y0f;

        float lg = 0.f;
        const float* qp = &qproj[w][h * QS];
        const float* kr = &kk[((b * NP + p) * NH + h) * HD];
        #pragma unroll
        for (int d = 0; d < HD; ++d) lg += qp[d] * kr[d];
        float m = fmaxf(lg, __shfl_xor(lg, 1, 4));
        m = fmaxf(m, __shfl_xor(m, 2, 4));
        float e = __expf(lg - m);
        float ssum = e + __shfl_xor(e, 1, 4);
        ssum += __shfl_xor(ssum, 2, 4);
        attnw[w][lane] = e / ssum;
    }
    __syncthreads();

    // phase 5: bilinear V sampling. 32 lanes = channels, 2 (h,p) pairs per iter.
    {
        int half = lane >> 5, d = lane & 31;
        const float* vb0 = value + (size_t)b * NV * EMB + d;
        for (int t = 0; t < 16; ++t) {
            int hp = t * 2 + half;
            int h = hp >> 2;
            int ix0 = six0[w][hp], iy0 = siy0[w][hp];
            float fx = sfx[w][hp], fy = sfy[w][hp];
            const float* vbase = vb0 + h * HD;
            float acc = 0.f;
            {   int xi = ix0,     yi = iy0;
                if ((unsigned)xi < IMG_W && (unsigned)yi < IMG_H)
                    acc += (1.f - fx) * (1.f - fy) * vbase[(size_t)(yi * IMG_W + xi) * EMB]; }
            {   int xi = ix0 + 1, yi = iy0;
                if ((unsigned)xi < IMG_W && (unsigned)yi < IMG_H)
                    acc += fx * (1.f - fy) * vbase[(size_t)(yi * IMG_W + xi) * EMB]; }
            {   int xi = ix0,     yi = iy0 + 1;
                if ((unsigned)xi < IMG_W && (unsigned)yi < IMG_H)
                    acc += (1.f - fx) * fy * vbase[(size_t)(yi * IMG_W + xi) * EMB]; }
            {   int xi = ix0 + 1, yi = iy0 + 1;
                if ((unsigned)xi < IMG_W && (unsigned)yi < IMG_H)
                    acc += fx * fy * vbase[(size_t)(yi * IMG_W + xi) * EMB]; }
            vs[w][hp * HD + d] = acc;
        }
    }
    __syncthreads();

    // phase 6: attention-weighted aggregation over p
    #pragma unroll
    for (int i = 0; i < 4; ++i) {
        int o = i * 64 + lane;
        int h = o >> 5, d = o & 31;
        float a = 0.f;
        #pragma unroll
        for (int p = 0; p < NP; ++p)
            a += attnw[w][h * 4 + p] * vs[w][(h * 4 + p) * HD + d];
        agg[w][h * QS + d] = a;
    }
    __syncthreads();

    // phase 7: Wv projection + store pre-row
    #pragma unroll
    for (int i = 0; i < 4; ++i) {
        int o = i * 64 + lane;
        int h = o >> 5, dd = o & 31;
        float s = sbv[dd];
        const float* ar = &agg[w][h * QS];
        const float* wr = &sWv[dd * WS];
        #pragma unroll
        for (int d = 0; d < HD; d += 4) {
            float4 a = *(const float4*)(ar + d);
            float4 ww = *(const float4*)(wr + d);
            s += a.x * ww.x + a.y * ww.y + a.z * ww.z + a.w * ww.w;
        }
        pre[(size_t)gq * EMB + o] = s;
    }
}

// ---------------- Kernel 3: out = pre @ Wo.T + bo + residual (in-place over d_out) ---
// grid: BS*NQ/64 blocks, 256 threads. Wave w: rows w*16..+15; lane owns cols lane+64j.
__global__ __launch_bounds__(256) void k3_gemm(
    const float* __restrict__ pre, float* __restrict__ outp,
    const float* __restrict__ query, const float* __restrict__ Wo,
    const float* __restrict__ bo)
{
    __shared__ float As[64 * EMB];   // 64 KB
    int tid = threadIdx.x;
    size_t r0 = (size_t)blockIdx.x * 64;
    {
        const float4* src = (const float4*)(pre + r0 * EMB);
        float4* dst = (float4*)As;
        for (int i = tid; i < 64 * EMB / 4; i += 256) dst[i] = src[i];
    }
    __syncthreads();

    int w = tid >> 6, lane = tid & 63;
    int rb = w * 16;
    float acc[16][4];
    #pragma unroll
    for (int r = 0; r < 16; ++r)
        #pragma unroll
        for (int j = 0; j < 4; ++j) acc[r][j] = 0.f;

    for (int kc = 0; kc < EMB / 4; ++kc) {
        float4 wreg[4];
        #pragma unroll
        for (int j = 0; j < 4; ++j)
            wreg[j] = *(const float4*)&Wo[(size_t)(lane + 64 * j) * EMB + kc * 4];
        #pragma unroll
        for (int r = 0; r < 16; ++r) {
            float4 a = *(const float4*)&As[(rb + r) * EMB + kc * 4];
            #pragma unroll
            for (int j = 0; j < 4; ++j)
                acc[r][j] += a.x * wreg[j].x + a.y * wreg[j].y
                           + a.z * wreg[j].z + a.w * wreg[j].w;
        }
    }

    #pragma unroll
    for (int r = 0; r < 16; ++r) {
        size_t row = r0 + rb + r;
        #pragma unroll
        for (int j = 0; j < 4; ++j) {
            int c = lane + 64 * j;
            outp[row * EMB + c] = acc[r][j] + bo[c] + query[row * EMB + c];
        }
    }
}

extern "C" void kernel_launch(void* const* d_in, const int* in_sizes, int n_in,
                              void* d_out, int out_size, void* d_ws, size_t ws_size,
                              hipStream_t stream) {
    const float* query = (const float*)d_in[0];
    const float* key   = (const float*)d_in[1];
    const float* value = (const float*)d_in[2];
    const float* refp  = (const float*)d_in[3];
    const float* Wq   = (const float*)d_in[4];
    const float* bq   = (const float*)d_in[5];
    const float* Wk   = (const float*)d_in[6];
    const float* bk   = (const float*)d_in[7];
    const float* Wv   = (const float*)d_in[8];
    const float* bv   = (const float*)d_in[9];
    const float* Woff = (const float*)d_in[10];
    const float* boff = (const float*)d_in[11];
    const float* Wo   = (const float*)d_in[12];
    const float* bo   = (const float*)d_in[13];
    (void)in_sizes; (void)n_in; (void)out_size; (void)ws_size;

    float* out = (float*)d_out;
    float* kk  = (float*)d_ws;       // 4*4*8*32 floats = 16 KB

    k1_keys<<<BS * NH, 64, 0, stream>>>(query, key, refp, Woff, boff, Wk, bk, kk);
    k2_main<<<BS * NQ / 4, 256, 0, stream>>>(query, value, refp, Wq, bq, Wv, bv,
                                             Woff, boff, kk, out);
    // in-place: each block stages its own 64 rows to LDS before overwriting them
    k3_gemm<<<BS * NQ / 64, 256, 0, stream>>>(out, out, query, Wo, bo);
}

// Round 2
// 389.686 us; speedup vs baseline: 1.3866x; 1.3866x over previous
//
#include <hip/hip_runtime.h>
#include <math.h>

#define NH   8
#define HD   32
#define NP   4
#define EMB  256
#define IMG_H 100
#define IMG_W 100
#define NQ   10000
#define NV   10000
#define BS   4

#define WS 34   // weight LDS stride: float2-aligned (8B), banks (2*dd+d)%32 -> conflict-free
#define QS 36   // qld stride: float4-aligned (16B), 8 rows -> banks (4h+d)%32 distinct
#define AS 34   // agg stride: float2-aligned, 8 rows -> banks (2h+d)%32 distinct

#define FENCE() asm volatile("" ::: "memory")

// ---------------- Kernel 1: precompute K = Wk * grid_sample(key, grids[:, :1]) + bk ----
__global__ __launch_bounds__(64) void k1_keys(
    const float* __restrict__ query, const float* __restrict__ key,
    const float* __restrict__ refp,  const float* __restrict__ Woff,
    const float* __restrict__ boff,  const float* __restrict__ Wk,
    const float* __restrict__ bk,    float* __restrict__ kk)
{
    int b = blockIdx.x >> 3, h = blockIdx.x & 7;
    __shared__ float q0[HD];
    __shared__ float off[8];
    __shared__ float ks[NP][HD];
    int l = threadIdx.x;

    if (l < HD) q0[l] = query[(size_t)(b * NQ) * EMB + h * HD + l];
    __syncthreads();

    if (l < 8) {
        float s = boff[l];
        #pragma unroll
        for (int d = 0; d < HD; ++d) s += q0[d] * Woff[l * HD + d];
        off[l] = s;
    }
    __syncthreads();

    if (l < HD) {
        float refx = refp[(size_t)(b * NQ) * 2 + 0];
        float refy = refp[(size_t)(b * NQ) * 2 + 1];
        for (int p = 0; p < NP; ++p) {
            float x = refx * IMG_W + off[p * 2 + 0] - 0.5f;
            float y = refy * IMG_H + off[p * 2 + 1] - 0.5f;
            float x0f = floorf(x), y0f = floorf(y);
            int ix0 = (int)x0f, iy0 = (int)y0f;
            float fx = x - x0f, fy = y - y0f;
            float acc = 0.f;
            #pragma unroll
            for (int cy = 0; cy < 2; ++cy)
                #pragma unroll
                for (int cx = 0; cx < 2; ++cx) {
                    int xi = ix0 + cx, yi = iy0 + cy;
                    if ((unsigned)xi < IMG_W && (unsigned)yi < IMG_H) {
                        float wgt = (cx ? fx : 1.f - fx) * (cy ? fy : 1.f - fy);
                        acc += wgt * key[((size_t)b * NV + yi * IMG_W + xi) * EMB + h * HD + l];
                    }
                }
            ks[p][l] = acc;
        }
    }
    __syncthreads();

    for (int t = 0; t < 2; ++t) {
        int idx = l + 64 * t;
        int p = idx >> 5, dout = idx & 31;
        float s = bk[dout];
        #pragma unroll
        for (int d = 0; d < HD; ++d) s += Wk[dout * HD + d] * ks[p][d];
        kk[((b * NP + p) * NH + h) * HD + dout] = s;
    }
}

// ---------------- Kernel 2: per-query pipeline, one independent wave per query -------
// 4 waves/block; only ONE __syncthreads (weight staging); all later phases are
// intra-wave (in-order DS + compiler fences).
__global__ __launch_bounds__(256) void k2_main(
    const float* __restrict__ query, const float* __restrict__ value,
    const float* __restrict__ refp,
    const float* __restrict__ Wq, const float* __restrict__ bq,
    const float* __restrict__ Wv, const float* __restrict__ bv,
    const float* __restrict__ Woff, const float* __restrict__ boff,
    const float* __restrict__ kk, float* __restrict__ pre)
{
    __shared__ float sWq[HD * WS];
    __shared__ float sWv[HD * WS];
    __shared__ float sWoff[8 * WS];
    __shared__ float sbq[HD], sbv[HD], sboff[8];
    __shared__ float qld[4][NH * QS];
    __shared__ float offs[4][64];
    __shared__ float attnw[4][32];
    __shared__ int   six0[4][32], siy0[4][32];
    __shared__ float sfx[4][32], sfy[4][32];
    __shared__ float aggL[4][NH * AS];

    int tid = threadIdx.x;
    for (int i = tid; i < HD * HD; i += 256) {
        sWq[(i >> 5) * WS + (i & 31)] = Wq[i];
        sWv[(i >> 5) * WS + (i & 31)] = Wv[i];
    }
    for (int i = tid; i < 8 * HD; i += 256) sWoff[(i >> 5) * WS + (i & 31)] = Woff[i];
    if (tid < HD) { sbq[tid] = bq[tid]; sbv[tid] = bv[tid]; }
    if (tid < 8)  sboff[tid] = boff[tid];

    int w = tid >> 6, lane = tid & 63;
    int gq = blockIdx.x * 4 + w;
    int b = gq / NQ;

    // phase 1: query row -> LDS (float4, conflict-free)
    float4 qv = *(const float4*)(query + (size_t)gq * EMB + lane * 4);
    { int e = lane * 4; *(float4*)&qld[w][(e >> 5) * QS + (e & 31)] = qv; }
    float refx = refp[(size_t)gq * 2 + 0];
    float refy = refp[(size_t)gq * 2 + 1];
    __syncthreads();   // weights + qld ready

    int h = lane >> 3, t = lane & 7;     // lane owns head h, column group t

    // register-cache q[h,:]
    float qr[HD];
    #pragma unroll
    for (int d = 0; d < HD; d += 2) {
        float2 v2 = *(const float2*)&qld[w][h * QS + d];
        qr[d] = v2.x; qr[d + 1] = v2.y;
    }

    // phase 3: sampling offsets — lane (h, j=t) computes one of 8 offsets for its head
    {
        float s = sboff[t];
        #pragma unroll
        for (int d = 0; d < HD; d += 2) {
            float2 ww = *(const float2*)&sWoff[t * WS + d];
            s += qr[d] * ww.x + qr[d + 1] * ww.y;
        }
        offs[w][h * 8 + t] = s;
    }

    // phase 2+4: qproj (dd = t+8k) fused directly into logits, in-register softmax
    float qp[4];
    #pragma unroll
    for (int k = 0; k < 4; ++k) {
        int dd = t + 8 * k;
        float s = sbq[dd];
        #pragma unroll
        for (int d = 0; d < HD; d += 2) {
            float2 ww = *(const float2*)&sWq[dd * WS + d];
            s += qr[d] * ww.x + qr[d + 1] * ww.y;
        }
        qp[k] = s;
    }
    float plog[NP];
    #pragma unroll
    for (int p = 0; p < NP; ++p) {
        const float* kr = &kk[((b * NP + p) * NH + h) * HD];
        float s = 0.f;
        #pragma unroll
        for (int k = 0; k < 4; ++k) s += qp[k] * kr[t + 8 * k];
        plog[p] = s;
    }
    #pragma unroll
    for (int p = 0; p < NP; ++p) {
        plog[p] += __shfl_xor(plog[p], 1, 8);
        plog[p] += __shfl_xor(plog[p], 2, 8);
        plog[p] += __shfl_xor(plog[p], 4, 8);
    }
    {
        float mm = fmaxf(fmaxf(plog[0], plog[1]), fmaxf(plog[2], plog[3]));
        float e0 = __expf(plog[0] - mm), e1 = __expf(plog[1] - mm);
        float e2 = __expf(plog[2] - mm), e3 = __expf(plog[3] - mm);
        float inv = 1.f / (e0 + e1 + e2 + e3);
        if (t < 4) {
            float a = (t == 0) ? e0 : (t == 1) ? e1 : (t == 2) ? e2 : e3;
            attnw[w][h * 4 + t] = a * inv;
        }
    }
    FENCE();

    // sampling setup: lanes<32, one (h2,p) each
    if (lane < 32) {
        int h2 = lane >> 2, p = lane & 3;
        float x = refx * IMG_W + offs[w][h2 * 8 + p * 2 + 0] - 0.5f;
        float y = refy * IMG_H + offs[w][h2 * 8 + p * 2 + 1] - 0.5f;
        float x0f = floorf(x), y0f = floorf(y);
        six0[w][lane] = (int)x0f; siy0[w][lane] = (int)y0f;
        sfx[w][lane] = x - x0f;  sfy[w][lane] = y - y0f;
    }
    FENCE();

    // phase 5+6: bilinear V gather fused with attention-weighted aggregation
    {
        int half = lane >> 5, d = lane & 31;
        const float* vb = value + (size_t)b * NV * EMB + d;
        #pragma unroll
        for (int i = 0; i < 4; ++i) {
            int hh = i * 2 + half;
            const float* vbase = vb + hh * HD;
            float acc = 0.f;
            #pragma unroll
            for (int p = 0; p < NP; ++p) {
                int hp = hh * 4 + p;
                int ix0 = six0[w][hp], iy0 = siy0[w][hp];
                float fx = sfx[w][hp], fy = sfy[w][hp];
                float aw = attnw[w][hp];
                float s = 0.f;
                {   int xi = ix0,     yi = iy0;
                    if ((unsigned)xi < IMG_W && (unsigned)yi < IMG_H)
                        s += (1.f - fx) * (1.f - fy) * vbase[(size_t)(yi * IMG_W + xi) * EMB]; }
                {   int xi = ix0 + 1, yi = iy0;
                    if ((unsigned)xi < IMG_W && (unsigned)yi < IMG_H)
                        s += fx * (1.f - fy) * vbase[(size_t)(yi * IMG_W + xi) * EMB]; }
                {   int xi = ix0,     yi = iy0 + 1;
                    if ((unsigned)xi < IMG_W && (unsigned)yi < IMG_H)
                        s += (1.f - fx) * fy * vbase[(size_t)(yi * IMG_W + xi) * EMB]; }
                {   int xi = ix0 + 1, yi = iy0 + 1;
                    if ((unsigned)xi < IMG_W && (unsigned)yi < IMG_H)
                        s += fx * fy * vbase[(size_t)(yi * IMG_W + xi) * EMB]; }
                acc += aw * s;
            }
            aggL[w][hh * AS + d] = acc;
        }
    }
    FENCE();

    // phase 7: Wv projection on aggregated samples, store pre-row
    {
        float ar[HD];
        #pragma unroll
        for (int d = 0; d < HD; d += 2) {
            float2 v2 = *(const float2*)&aggL[w][h * AS + d];
            ar[d] = v2.x; ar[d + 1] = v2.y;
        }
        float* prow = pre + (size_t)gq * EMB + h * HD;
        #pragma unroll
        for (int k = 0; k < 4; ++k) {
            int dd = t + 8 * k;
            float s = sbv[dd];
            #pragma unroll
            for (int d = 0; d < HD; d += 2) {
                float2 ww = *(const float2*)&sWv[dd * WS + d];
                s += ar[d] * ww.x + ar[d + 1] * ww.y;
            }
            prow[dd] = s;
        }
    }
}

// ---------------- Kernel 3: out = pre @ Wo.T + bo + residual (in-place over d_out) ---
__global__ __launch_bounds__(256) void k3_gemm(
    const float* __restrict__ pre, float* __restrict__ outp,
    const float* __restrict__ query, const float* __restrict__ Wo,
    const float* __restrict__ bo)
{
    __shared__ float As[64 * EMB];   // 64 KB
    int tid = threadIdx.x;
    size_t r0 = (size_t)blockIdx.x * 64;
    {
        const float4* src = (const float4*)(pre + r0 * EMB);
        float4* dst = (float4*)As;
        for (int i = tid; i < 64 * EMB / 4; i += 256) dst[i] = src[i];
    }
    __syncthreads();

    int w = tid >> 6, lane = tid & 63;
    int rb = w * 16;
    float acc[16][4];
    #pragma unroll
    for (int r = 0; r < 16; ++r)
        #pragma unroll
        for (int j = 0; j < 4; ++j) acc[r][j] = 0.f;

    for (int kc = 0; kc < EMB / 4; ++kc) {
        float4 wreg[4];
        #pragma unroll
        for (int j = 0; j < 4; ++j)
            wreg[j] = *(const float4*)&Wo[(size_t)(lane + 64 * j) * EMB + kc * 4];
        #pragma unroll
        for (int r = 0; r < 16; ++r) {
            float4 a = *(const float4*)&As[(rb + r) * EMB + kc * 4];
            #pragma unroll
            for (int j = 0; j < 4; ++j)
                acc[r][j] += a.x * wreg[j].x + a.y * wreg[j].y
                           + a.z * wreg[j].z + a.w * wreg[j].w;
        }
    }

    #pragma unroll
    for (int r = 0; r < 16; ++r) {
        size_t row = r0 + rb + r;
        #pragma unroll
        for (int j = 0; j < 4; ++j) {
            int c = lane + 64 * j;
            outp[row * EMB + c] = acc[r][j] + bo[c] + query[row * EMB + c];
        }
    }
}

extern "C" void kernel_launch(void* const* d_in, const int* in_sizes, int n_in,
                              void* d_out, int out_size, void* d_ws, size_t ws_size,
                              hipStream_t stream) {
    const float* query = (const float*)d_in[0];
    const float* key   = (const float*)d_in[1];
    const float* value = (const float*)d_in[2];
    const float* refp  = (const float*)d_in[3];
    const float* Wq   = (const float*)d_in[4];
    const float* bq   = (const float*)d_in[5];
    const float* Wk   = (const float*)d_in[6];
    const float* bk   = (const float*)d_in[7];
    const float* Wv   = (const float*)d_in[8];
    const float* bv   = (const float*)d_in[9];
    const float* Woff = (const float*)d_in[10];
    const float* boff = (const float*)d_in[11];
    const float* Wo   = (const float*)d_in[12];
    const float* bo   = (const float*)d_in[13];
    (void)in_sizes; (void)n_in; (void)out_size; (void)ws_size;

    float* out = (float*)d_out;
    float* kk  = (float*)d_ws;       // 4*4*8*32 floats = 16 KB

    k1_keys<<<BS * NH, 64, 0, stream>>>(query, key, refp, Woff, boff, Wk, bk, kk);
    k2_main<<<BS * NQ / 4, 256, 0, stream>>>(query, value, refp, Wq, bq, Wv, bv,
                                             Woff, boff, kk, out);
    k3_gemm<<<BS * NQ / 64, 256, 0, stream>>>(out, out, query, Wo, bo);
}

// Round 3
// 142.394 us; speedup vs baseline: 3.7948x; 2.7367x over previous
//
#include <hip/hip_runtime.h>
#include <hip/hip_bf16.h>
#include <math.h>

#define NH   8
#define HD   32
#define NP   4
#define EMB  256
#define IMG_H 100
#define IMG_W 100
#define NQ   10000
#define NV   10000
#define BS   4

#define WS 34   // weight LDS stride: float2-aligned, conflict-free
#define QS 36   // qld stride: float4-aligned
#define AS 34   // agg stride: float2-aligned

#define FENCE() asm volatile("" ::: "memory")

typedef __attribute__((ext_vector_type(8))) short bf16x8;
typedef __attribute__((ext_vector_type(4))) float f32x4;

// ws layout
#define KK_OFF    0
#define WOB_OFF   16384
#define PREB_OFF  (16384 + 131072)
#define WS_NEEDED ((size_t)PREB_OFF + (size_t)BS * NQ * EMB * 2)

// ---------------- Kernel 1: K = Wk * grid_sample(key, grids[:, :1]) + bk ------------
__global__ __launch_bounds__(64) void k1_keys(
    const float* __restrict__ query, const float* __restrict__ key,
    const float* __restrict__ refp,  const float* __restrict__ Woff,
    const float* __restrict__ boff,  const float* __restrict__ Wk,
    const float* __restrict__ bk,    float* __restrict__ kk)
{
    int b = blockIdx.x >> 3, h = blockIdx.x & 7;
    __shared__ float q0[HD];
    __shared__ float off[8];
    __shared__ float ks[NP][HD];
    int l = threadIdx.x;

    if (l < HD) q0[l] = query[(size_t)(b * NQ) * EMB + h * HD + l];
    __syncthreads();

    if (l < 8) {
        float s = boff[l];
        #pragma unroll
        for (int d = 0; d < HD; ++d) s += q0[d] * Woff[l * HD + d];
        off[l] = s;
    }
    __syncthreads();

    if (l < HD) {
        float refx = refp[(size_t)(b * NQ) * 2 + 0];
        float refy = refp[(size_t)(b * NQ) * 2 + 1];
        for (int p = 0; p < NP; ++p) {
            float x = refx * IMG_W + off[p * 2 + 0] - 0.5f;
            float y = refy * IMG_H + off[p * 2 + 1] - 0.5f;
            float x0f = floorf(x), y0f = floorf(y);
            int ix0 = (int)x0f, iy0 = (int)y0f;
            float fx = x - x0f, fy = y - y0f;
            float acc = 0.f;
            #pragma unroll
            for (int cy = 0; cy < 2; ++cy)
                #pragma unroll
                for (int cx = 0; cx < 2; ++cx) {
                    int xi = ix0 + cx, yi = iy0 + cy;
                    if ((unsigned)xi < IMG_W && (unsigned)yi < IMG_H) {
                        float wgt = (cx ? fx : 1.f - fx) * (cy ? fy : 1.f - fy);
                        acc += wgt * key[((size_t)b * NV + yi * IMG_W + xi) * EMB + h * HD + l];
                    }
                }
            ks[p][l] = acc;
        }
    }
    __syncthreads();

    for (int t = 0; t < 2; ++t) {
        int idx = l + 64 * t;
        int p = idx >> 5, dout = idx & 31;
        float s = bk[dout];
        #pragma unroll
        for (int d = 0; d < HD; ++d) s += Wk[dout * HD + d] * ks[p][d];
        kk[((b * NP + p) * NH + h) * HD + dout] = s;
    }
}

// ---------------- Kernel: Wo f32 -> bf16 ---------------------------------------------
__global__ __launch_bounds__(256) void kconv_wo(const float* __restrict__ Wo,
                                               __hip_bfloat16* __restrict__ wob)
{
    int i = (blockIdx.x * 256 + threadIdx.x) * 4;
    float4 v = *(const float4*)(Wo + i);
    wob[i + 0] = __float2bfloat16(v.x);
    wob[i + 1] = __float2bfloat16(v.y);
    wob[i + 2] = __float2bfloat16(v.z);
    wob[i + 3] = __float2bfloat16(v.w);
}

// ---------------- Kernel 2: per-query pipeline, one independent wave per query -------
template<int BF16OUT>
__global__ __launch_bounds__(256) void k2_main(
    const float* __restrict__ query, const float* __restrict__ value,
    const float* __restrict__ refp,
    const float* __restrict__ Wq, const float* __restrict__ bq,
    const float* __restrict__ Wv, const float* __restrict__ bv,
    const float* __restrict__ Woff, const float* __restrict__ boff,
    const float* __restrict__ kk, float* __restrict__ pre,
    __hip_bfloat16* __restrict__ preb)
{
    __shared__ float sWq[HD * WS];
    __shared__ float sWv[HD * WS];
    __shared__ float sWoff[8 * WS];
    __shared__ float sbq[HD], sbv[HD], sboff[8];
    __shared__ float qld[4][NH * QS];
    __shared__ float offs[4][64];
    __shared__ float attnw[4][32];
    __shared__ int   six0[4][32], siy0[4][32];
    __shared__ float sfx[4][32], sfy[4][32];
    __shared__ float aggL[4][NH * AS];

    int tid = threadIdx.x;
    for (int i = tid; i < HD * HD; i += 256) {
        sWq[(i >> 5) * WS + (i & 31)] = Wq[i];
        sWv[(i >> 5) * WS + (i & 31)] = Wv[i];
    }
    for (int i = tid; i < 8 * HD; i += 256) sWoff[(i >> 5) * WS + (i & 31)] = Woff[i];
    if (tid < HD) { sbq[tid] = bq[tid]; sbv[tid] = bv[tid]; }
    if (tid < 8)  sboff[tid] = boff[tid];

    int w = tid >> 6, lane = tid & 63;
    int gq = blockIdx.x * 4 + w;
    int b = gq / NQ;

    float4 qv = *(const float4*)(query + (size_t)gq * EMB + lane * 4);
    { int e = lane * 4; *(float4*)&qld[w][(e >> 5) * QS + (e & 31)] = qv; }
    float refx = refp[(size_t)gq * 2 + 0];
    float refy = refp[(size_t)gq * 2 + 1];
    __syncthreads();   // weights + qld ready

    int h = lane >> 3, t = lane & 7;

    float qr[HD];
    #pragma unroll
    for (int d = 0; d < HD; d += 2) {
        float2 v2 = *(const float2*)&qld[w][h * QS + d];
        qr[d] = v2.x; qr[d + 1] = v2.y;
    }

    // sampling offsets: lane (h, j=t)
    {
        float s = sboff[t];
        #pragma unroll
        for (int d = 0; d < HD; d += 2) {
            float2 ww = *(const float2*)&sWoff[t * WS + d];
            s += qr[d] * ww.x + qr[d + 1] * ww.y;
        }
        offs[w][h * 8 + t] = s;
    }

    // q-proj fused into logits, in-register softmax
    float qp[4];
    #pragma unroll
    for (int k = 0; k < 4; ++k) {
        int dd = t + 8 * k;
        float s = sbq[dd];
        #pragma unroll
        for (int d = 0; d < HD; d += 2) {
            float2 ww = *(const float2*)&sWq[dd * WS + d];
            s += qr[d] * ww.x + qr[d + 1] * ww.y;
        }
        qp[k] = s;
    }
    float plog[NP];
    #pragma unroll
    for (int p = 0; p < NP; ++p) {
        const float* kr = &kk[((b * NP + p) * NH + h) * HD];
        float s = 0.f;
        #pragma unroll
        for (int k = 0; k < 4; ++k) s += qp[k] * kr[t + 8 * k];
        plog[p] = s;
    }
    #pragma unroll
    for (int p = 0; p < NP; ++p) {
        plog[p] += __shfl_xor(plog[p], 1, 8);
        plog[p] += __shfl_xor(plog[p], 2, 8);
        plog[p] += __shfl_xor(plog[p], 4, 8);
    }
    {
        float mm = fmaxf(fmaxf(plog[0], plog[1]), fmaxf(plog[2], plog[3]));
        float e0 = __expf(plog[0] - mm), e1 = __expf(plog[1] - mm);
        float e2 = __expf(plog[2] - mm), e3 = __expf(plog[3] - mm);
        float inv = 1.f / (e0 + e1 + e2 + e3);
        if (t < 4) {
            float a = (t == 0) ? e0 : (t == 1) ? e1 : (t == 2) ? e2 : e3;
            attnw[w][h * 4 + t] = a * inv;
        }
    }
    FENCE();

    if (lane < 32) {
        int h2 = lane >> 2, p = lane & 3;
        float x = refx * IMG_W + offs[w][h2 * 8 + p * 2 + 0] - 0.5f;
        float y = refy * IMG_H + offs[w][h2 * 8 + p * 2 + 1] - 0.5f;
        float x0f = floorf(x), y0f = floorf(y);
        six0[w][lane] = (int)x0f; siy0[w][lane] = (int)y0f;
        sfx[w][lane] = x - x0f;  sfy[w][lane] = y - y0f;
    }
    FENCE();

    // bilinear V gather, branchless, batched loads, fused aggregation
    {
        int half = lane >> 5, d = lane & 31;
        const float* vb = value + (size_t)b * NV * EMB + d;
        #pragma unroll
        for (int i = 0; i < 4; ++i) {
            int hh = i * 2 + half;
            const float* vbase = vb + hh * HD;
            float wgt[16]; int goff[16];
            #pragma unroll
            for (int p = 0; p < NP; ++p) {
                int hp = hh * 4 + p;
                int ix0 = six0[w][hp], iy0 = siy0[w][hp];
                float fx = sfx[w][hp], fy = sfy[w][hp];
                float aw = attnw[w][hp];
                float wx0 = 1.f - fx, wy0 = 1.f - fy;
                #pragma unroll
                for (int c = 0; c < 4; ++c) {
                    int cx = c & 1, cy = c >> 1;
                    int xi = ix0 + cx, yi = iy0 + cy;
                    bool valid = ((unsigned)xi < IMG_W) & ((unsigned)yi < IMG_H);
                    int xc = min(max(xi, 0), IMG_W - 1);
                    int yc = min(max(yi, 0), IMG_H - 1);
                    float wv = (cx ? fx : wx0) * (cy ? fy : wy0) * aw;
                    wgt[p * 4 + c] = valid ? wv : 0.f;
                    goff[p * 4 + c] = (yc * IMG_W + xc) * EMB;
                }
            }
            float vals[16];
            #pragma unroll
            for (int u = 0; u < 16; ++u) vals[u] = vbase[goff[u]];
            float acc = 0.f;
            #pragma unroll
            for (int u = 0; u < 16; ++u) acc += wgt[u] * vals[u];
            aggL[w][hh * AS + d] = acc;
        }
    }
    FENCE();

    // Wv projection, store pre-row (f32 or bf16)
    {
        float ar[HD];
        #pragma unroll
        for (int d = 0; d < HD; d += 2) {
            float2 v2 = *(const float2*)&aggL[w][h * AS + d];
            ar[d] = v2.x; ar[d + 1] = v2.y;
        }
        float outv[4];
        #pragma unroll
        for (int k = 0; k < 4; ++k) {
            int dd = t + 8 * k;
            float s = sbv[dd];
            #pragma unroll
            for (int d = 0; d < HD; d += 2) {
                float2 ww = *(const float2*)&sWv[dd * WS + d];
                s += ar[d] * ww.x + ar[d + 1] * ww.y;
            }
            outv[k] = s;
        }
        if (BF16OUT) {
            __hip_bfloat16* prow = preb + (size_t)gq * EMB + h * HD;
            #pragma unroll
            for (int k = 0; k < 4; ++k) prow[t + 8 * k] = __float2bfloat16(outv[k]);
        } else {
            float* prow = pre + (size_t)gq * EMB + h * HD;
            #pragma unroll
            for (int k = 0; k < 4; ++k) prow[t + 8 * k] = outv[k];
        }
    }
}

// ---------------- Kernel 3a: MFMA bf16 GEMM out = preb @ wob^T + bo + residual -------
// grid 625 blocks x 256 thr; wave w owns cols [w*64, w*64+64); block owns 64 rows.
__global__ __launch_bounds__(256) void k3_mfma(
    const __hip_bfloat16* __restrict__ preb, const __hip_bfloat16* __restrict__ wob,
    float* __restrict__ outp, const float* __restrict__ query,
    const float* __restrict__ bo)
{
    int w = threadIdx.x >> 6, lane = threadIdx.x & 63;
    size_t m0 = (size_t)blockIdx.x * 64;
    int n0 = w * 64;
    int lr = lane & 15, lg = lane >> 4;

    const short* pa = (const short*)preb;
    const short* pb = (const short*)wob;

    f32x4 acc[4][4];
    #pragma unroll
    for (int mt = 0; mt < 4; ++mt)
        #pragma unroll
        for (int nt = 0; nt < 4; ++nt) acc[mt][nt] = (f32x4){0.f, 0.f, 0.f, 0.f};

    #pragma unroll
    for (int k0 = 0; k0 < EMB; k0 += 32) {
        bf16x8 af[4], bf[4];
        #pragma unroll
        for (int mt = 0; mt < 4; ++mt)
            af[mt] = *(const bf16x8*)(pa + (m0 + mt * 16 + lr) * EMB + k0 + lg * 8);
        #pragma unroll
        for (int nt = 0; nt < 4; ++nt)
            bf[nt] = *(const bf16x8*)(pb + (size_t)(n0 + nt * 16 + lr) * EMB + k0 + lg * 8);
        #pragma unroll
        for (int mt = 0; mt < 4; ++mt)
            #pragma unroll
            for (int nt = 0; nt < 4; ++nt)
                acc[mt][nt] = __builtin_amdgcn_mfma_f32_16x16x32_bf16(
                    af[mt], bf[nt], acc[mt][nt], 0, 0, 0);
    }

    float bov[4];
    #pragma unroll
    for (int nt = 0; nt < 4; ++nt) bov[nt] = bo[n0 + nt * 16 + lr];

    #pragma unroll
    for (int mt = 0; mt < 4; ++mt)
        #pragma unroll
        for (int q = 0; q < 4; ++q) {
            size_t row = m0 + mt * 16 + lg * 4 + q;
            const float* qrow = query + row * EMB;
            float* orow = outp + row * EMB;
            #pragma unroll
            for (int nt = 0; nt < 4; ++nt) {
                int col = n0 + nt * 16 + lr;
                orow[col] = acc[mt][nt][q] + bov[nt] + qrow[col];
            }
        }
}

// ---------------- Kernel 3b: f32 fallback (in-place over d_out) ----------------------
__global__ __launch_bounds__(256) void k3_gemm(
    const float* __restrict__ pre, float* __restrict__ outp,
    const float* __restrict__ query, const float* __restrict__ Wo,
    const float* __restrict__ bo)
{
    __shared__ float As[64 * EMB];
    int tid = threadIdx.x;
    size_t r0 = (size_t)blockIdx.x * 64;
    {
        const float4* src = (const float4*)(pre + r0 * EMB);
        float4* dst = (float4*)As;
        for (int i = tid; i < 64 * EMB / 4; i += 256) dst[i] = src[i];
    }
    __syncthreads();

    int w = tid >> 6, lane = tid & 63;
    int rb = w * 16;
    float acc[16][4];
    #pragma unroll
    for (int r = 0; r < 16; ++r)
        #pragma unroll
        for (int j = 0; j < 4; ++j) acc[r][j] = 0.f;

    for (int kc = 0; kc < EMB / 4; ++kc) {
        float4 wreg[4];
        #pragma unroll
        for (int j = 0; j < 4; ++j)
            wreg[j] = *(const float4*)&Wo[(size_t)(lane + 64 * j) * EMB + kc * 4];
        #pragma unroll
        for (int r = 0; r < 16; ++r) {
            float4 a = *(const float4*)&As[(rb + r) * EMB + kc * 4];
            #pragma unroll
            for (int j = 0; j < 4; ++j)
                acc[r][j] += a.x * wreg[j].x + a.y * wreg[j].y
                           + a.z * wreg[j].z + a.w * wreg[j].w;
        }
    }

    #pragma unroll
    for (int r = 0; r < 16; ++r) {
        size_t row = r0 + rb + r;
        #pragma unroll
        for (int j = 0; j < 4; ++j) {
            int c = lane + 64 * j;
            outp[row * EMB + c] = acc[r][j] + bo[c] + query[row * EMB + c];
        }
    }
}

extern "C" void kernel_launch(void* const* d_in, const int* in_sizes, int n_in,
                              void* d_out, int out_size, void* d_ws, size_t ws_size,
                              hipStream_t stream) {
    const float* query = (const float*)d_in[0];
    const float* key   = (const float*)d_in[1];
    const float* value = (const float*)d_in[2];
    const float* refp  = (const float*)d_in[3];
    const float* Wq   = (const float*)d_in[4];
    const float* bq   = (const float*)d_in[5];
    const float* Wk   = (const float*)d_in[6];
    const float* bk   = (const float*)d_in[7];
    const float* Wv   = (const float*)d_in[8];
    const float* bv   = (const float*)d_in[9];
    const float* Woff = (const float*)d_in[10];
    const float* boff = (const float*)d_in[11];
    const float* Wo   = (const float*)d_in[12];
    const float* bo   = (const float*)d_in[13];
    (void)in_sizes; (void)n_in; (void)out_size;

    float* out = (float*)d_out;
    char*  ws  = (char*)d_ws;
    float* kk  = (float*)(ws + KK_OFF);

    k1_keys<<<BS * NH, 64, 0, stream>>>(query, key, refp, Woff, boff, Wk, bk, kk);

    if (ws_size >= WS_NEEDED) {
        __hip_bfloat16* wob  = (__hip_bfloat16*)(ws + WOB_OFF);
        __hip_bfloat16* preb = (__hip_bfloat16*)(ws + PREB_OFF);
        kconv_wo<<<EMB * EMB / 1024, 256, 0, stream>>>(Wo, wob);
        k2_main<1><<<BS * NQ / 4, 256, 0, stream>>>(query, value, refp, Wq, bq, Wv, bv,
                                                    Woff, boff, kk, nullptr, preb);
        k3_mfma<<<BS * NQ / 64, 256, 0, stream>>>(preb, wob, out, query, bo);
    } else {
        k2_main<0><<<BS * NQ / 4, 256, 0, stream>>>(query, value, refp, Wq, bq, Wv, bv,
                                                    Woff, boff, kk, out, nullptr);
        k3_gemm<<<BS * NQ / 64, 256, 0, stream>>>(out, out, query, Wo, bo);
    }
}

// Round 4
// 120.096 us; speedup vs baseline: 4.4994x; 1.1857x over previous
//
#include <hip/hip_runtime.h>
#include <hip/hip_bf16.h>
#include <math.h>

#define NH   8
#define HD   32
#define NP   4
#define EMB  256
#define IMG_H 100
#define IMG_W 100
#define NQ   10000
#define NV   10000
#define BS   4

#define W4S 36   // weight/q/agg LDS stride: float4-aligned, banks (4*row+d)%32 conflict-free

#define FENCE() asm volatile("" ::: "memory")

typedef __attribute__((ext_vector_type(8))) short bf16x8;
typedef __attribute__((ext_vector_type(4))) float f32x4;

// ws layout
#define KK_OFF    0
#define WOB_OFF   16384
#define PREB_OFF  (16384 + 131072)
#define WS_NEEDED ((size_t)PREB_OFF + (size_t)BS * NQ * EMB * 2)

// ---------------- Kernel 1: K = Wk * grid_sample(key, grids[:, :1]) + bk ------------
__global__ __launch_bounds__(64) void k1_keys(
    const float* __restrict__ query, const float* __restrict__ key,
    const float* __restrict__ refp,  const float* __restrict__ Woff,
    const float* __restrict__ boff,  const float* __restrict__ Wk,
    const float* __restrict__ bk,    float* __restrict__ kk)
{
    int b = blockIdx.x >> 3, h = blockIdx.x & 7;
    __shared__ float q0[HD];
    __shared__ float off[8];
    __shared__ float ks[NP][HD];
    int l = threadIdx.x;

    if (l < HD) q0[l] = query[(size_t)(b * NQ) * EMB + h * HD + l];
    __syncthreads();

    if (l < 8) {
        float s = boff[l];
        #pragma unroll
        for (int d = 0; d < HD; ++d) s += q0[d] * Woff[l * HD + d];
        off[l] = s;
    }
    __syncthreads();

    if (l < HD) {
        float refx = refp[(size_t)(b * NQ) * 2 + 0];
        float refy = refp[(size_t)(b * NQ) * 2 + 1];
        for (int p = 0; p < NP; ++p) {
            float x = refx * IMG_W + off[p * 2 + 0] - 0.5f;
            float y = refy * IMG_H + off[p * 2 + 1] - 0.5f;
            float x0f = floorf(x), y0f = floorf(y);
            int ix0 = (int)x0f, iy0 = (int)y0f;
            float fx = x - x0f, fy = y - y0f;
            float acc = 0.f;
            #pragma unroll
            for (int cy = 0; cy < 2; ++cy)
                #pragma unroll
                for (int cx = 0; cx < 2; ++cx) {
                    int xi = ix0 + cx, yi = iy0 + cy;
                    if ((unsigned)xi < IMG_W && (unsigned)yi < IMG_H) {
                        float wgt = (cx ? fx : 1.f - fx) * (cy ? fy : 1.f - fy);
                        acc += wgt * key[((size_t)b * NV + yi * IMG_W + xi) * EMB + h * HD + l];
                    }
                }
            ks[p][l] = acc;
        }
    }
    __syncthreads();

    for (int t = 0; t < 2; ++t) {
        int idx = l + 64 * t;
        int p = idx >> 5, dout = idx & 31;
        float s = bk[dout];
        #pragma unroll
        for (int d = 0; d < HD; ++d) s += Wk[dout * HD + d] * ks[p][d];
        kk[((b * NP + p) * NH + h) * HD + dout] = s;
    }
}

// ---------------- Kernel: Wo f32 -> bf16 ---------------------------------------------
__global__ __launch_bounds__(256) void kconv_wo(const float* __restrict__ Wo,
                                               __hip_bfloat16* __restrict__ wob)
{
    int i = (blockIdx.x * 256 + threadIdx.x) * 4;
    float4 v = *(const float4*)(Wo + i);
    wob[i + 0] = __float2bfloat16(v.x);
    wob[i + 1] = __float2bfloat16(v.y);
    wob[i + 2] = __float2bfloat16(v.z);
    wob[i + 3] = __float2bfloat16(v.w);
}

// ---------------- Kernel 2: per-query pipeline, one independent wave per query -------
// Metadata (weights x attn, element offsets) computed ONCE per (h,p) by lanes<32,
// broadcast through LDS to the gather loop. One __syncthreads total.
template<int BF16OUT>
__global__ __launch_bounds__(256) void k2_main(
    const float* __restrict__ query, const float* __restrict__ value,
    const float* __restrict__ refp,
    const float* __restrict__ Wq, const float* __restrict__ bq,
    const float* __restrict__ Wv, const float* __restrict__ bv,
    const float* __restrict__ Woff, const float* __restrict__ boff,
    const float* __restrict__ kk, float* __restrict__ pre,
    __hip_bfloat16* __restrict__ preb)
{
    __shared__ float sWq[HD * W4S];
    __shared__ float sWv[HD * W4S];
    __shared__ float sWoff[8 * W4S];
    __shared__ float skk[NP * NH * HD];          // 4 KB, block-uniform batch
    __shared__ float sbq[HD], sbv[HD], sboff[8];
    __shared__ float qag[4][NH * W4S];           // query row, then reused for agg
    __shared__ float offs[4][64];
    __shared__ float attnw[4][32];
    __shared__ int   soff4[4][32][4];            // per (h,p): 4 corner element-offsets
    __shared__ float swgt4[4][32][4];            // per (h,p): 4 premultiplied weights

    int tid = threadIdx.x;
    for (int i = tid; i < HD * HD; i += 256) {
        int r = i >> 5, c = i & 31;
        sWq[r * W4S + c] = Wq[i];
        sWv[r * W4S + c] = Wv[i];
    }
    for (int i = tid; i < 8 * HD; i += 256) sWoff[(i >> 5) * W4S + (i & 31)] = Woff[i];
    if (tid < HD) { sbq[tid] = bq[tid]; sbv[tid] = bv[tid]; }
    if (tid < 8)  sboff[tid] = boff[tid];

    int b0 = (blockIdx.x * 4) / NQ;              // uniform: 4 | NQ
    *(float4*)&skk[tid * 4] = *(const float4*)(kk + b0 * (NP * NH * HD) + tid * 4);

    int w = tid >> 6, lane = tid & 63;
    int gq = blockIdx.x * 4 + w;
    int b = b0;

    float4 qv = *(const float4*)(query + (size_t)gq * EMB + lane * 4);
    { int e = lane * 4; *(float4*)&qag[w][(e >> 5) * W4S + (e & 31)] = qv; }
    float refx = refp[(size_t)gq * 2 + 0];
    float refy = refp[(size_t)gq * 2 + 1];
    __syncthreads();   // weights + skk + q rows ready

    int h = lane >> 3, t = lane & 7;

    // register-cache q[h,:] (float4 LDS reads, 8-way broadcast, conflict-free)
    float qr[HD];
    #pragma unroll
    for (int d = 0; d < HD; d += 4) {
        float4 v4 = *(const float4*)&qag[w][h * W4S + d];
        qr[d] = v4.x; qr[d + 1] = v4.y; qr[d + 2] = v4.z; qr[d + 3] = v4.w;
    }

    // sampling offsets: lane (h, j=t)
    {
        float s = sboff[t];
        const float* wr = &sWoff[t * W4S];
        #pragma unroll
        for (int d = 0; d < HD; d += 4) {
            float4 ww = *(const float4*)(wr + d);
            s += qr[d] * ww.x + qr[d+1] * ww.y + qr[d+2] * ww.z + qr[d+3] * ww.w;
        }
        offs[w][h * 8 + t] = s;
    }

    // q-proj fused into logits, in-register softmax
    float qp[4];
    #pragma unroll
    for (int k = 0; k < 4; ++k) {
        int dd = t + 8 * k;
        float s = sbq[dd];
        const float* wr = &sWq[dd * W4S];
        #pragma unroll
        for (int d = 0; d < HD; d += 4) {
            float4 ww = *(const float4*)(wr + d);
            s += qr[d] * ww.x + qr[d+1] * ww.y + qr[d+2] * ww.z + qr[d+3] * ww.w;
        }
        qp[k] = s;
    }
    float plog[NP];
    #pragma unroll
    for (int p = 0; p < NP; ++p) {
        const float* kr = &skk[(p * NH + h) * HD];
        float s = 0.f;
        #pragma unroll
        for (int k = 0; k < 4; ++k) s += qp[k] * kr[t + 8 * k];
        plog[p] = s;
    }
    #pragma unroll
    for (int p = 0; p < NP; ++p) {
        plog[p] += __shfl_xor(plog[p], 1, 8);
        plog[p] += __shfl_xor(plog[p], 2, 8);
        plog[p] += __shfl_xor(plog[p], 4, 8);
    }
    {
        float mm = fmaxf(fmaxf(plog[0], plog[1]), fmaxf(plog[2], plog[3]));
        float e0 = __expf(plog[0] - mm), e1 = __expf(plog[1] - mm);
        float e2 = __expf(plog[2] - mm), e3 = __expf(plog[3] - mm);
        float inv = 1.f / (e0 + e1 + e2 + e3);
        if (t < 4) {
            float a = (t == 0) ? e0 : (t == 1) ? e1 : (t == 2) ? e2 : e3;
            attnw[w][h * 4 + t] = a * inv;
        }
    }
    FENCE();

    // metadata: one (h2,p) per lane<32 — premultiplied weights + element offsets
    if (lane < 32) {
        int h2 = lane >> 2, p = lane & 3;
        float x = refx * IMG_W + offs[w][h2 * 8 + p * 2 + 0] - 0.5f;
        float y = refy * IMG_H + offs[w][h2 * 8 + p * 2 + 1] - 0.5f;
        float x0f = floorf(x), y0f = floorf(y);
        int ix0 = (int)x0f, iy0 = (int)y0f;
        float fx = x - x0f, fy = y - y0f;
        float aw = attnw[w][lane];
        float wx1 = fx * aw, wx0 = aw - wx1;
        int bbase = b * (NV * EMB) + h2 * HD;
        int   o4[4]; float g4[4];
        #pragma unroll
        for (int c = 0; c < 4; ++c) {
            int cx = c & 1, cy = c >> 1;
            int xi = ix0 + cx, yi = iy0 + cy;
            bool valid = ((unsigned)xi < IMG_W) & ((unsigned)yi < IMG_H);
            int xc = min(max(xi, 0), IMG_W - 1);
            int yc = min(max(yi, 0), IMG_H - 1);
            o4[c] = bbase + (yc * IMG_W + xc) * EMB;
            float wv = (cx ? wx1 : wx0) * (cy ? fy : 1.f - fy);
            g4[c] = valid ? wv : 0.f;
        }
        int4   ov = {o4[0], o4[1], o4[2], o4[3]};
        float4 gv = {g4[0], g4[1], g4[2], g4[3]};
        *(int4*)&soff4[w][lane][0]   = ov;
        *(float4*)&swgt4[w][lane][0] = gv;
    }
    FENCE();

    // gather: broadcast metadata, batched coalesced loads, fused weighted sum
    {
        int half = lane >> 5, dcol = lane & 31;
        #pragma unroll
        for (int i = 0; i < 4; ++i) {
            int hh = i * 2 + half;
            float vals[16], wv[16];
            #pragma unroll
            for (int p = 0; p < NP; ++p) {
                int hp = hh * 4 + p;
                int4   o4 = *(const int4*)&soff4[w][hp][0];
                float4 g4 = *(const float4*)&swgt4[w][hp][0];
                vals[p*4+0] = value[(unsigned)(o4.x + dcol)];
                vals[p*4+1] = value[(unsigned)(o4.y + dcol)];
                vals[p*4+2] = value[(unsigned)(o4.z + dcol)];
                vals[p*4+3] = value[(unsigned)(o4.w + dcol)];
                wv[p*4+0] = g4.x; wv[p*4+1] = g4.y; wv[p*4+2] = g4.z; wv[p*4+3] = g4.w;
            }
            float acc = 0.f;
            #pragma unroll
            for (int u = 0; u < 16; ++u) acc += wv[u] * vals[u];
            qag[w][hh * W4S + dcol] = acc;    // overwrites own wave's q row (dead)
        }
    }
    FENCE();

    // Wv projection, store pre-row (f32 or bf16)
    {
        float ar[HD];
        #pragma unroll
        for (int d = 0; d < HD; d += 4) {
            float4 v4 = *(const float4*)&qag[w][h * W4S + d];
            ar[d] = v4.x; ar[d + 1] = v4.y; ar[d + 2] = v4.z; ar[d + 3] = v4.w;
        }
        float outv[4];
        #pragma unroll
        for (int k = 0; k < 4; ++k) {
            int dd = t + 8 * k;
            float s = sbv[dd];
            const float* wr = &sWv[dd * W4S];
            #pragma unroll
            for (int d = 0; d < HD; d += 4) {
                float4 ww = *(const float4*)(wr + d);
                s += ar[d] * ww.x + ar[d+1] * ww.y + ar[d+2] * ww.z + ar[d+3] * ww.w;
            }
            outv[k] = s;
        }
        if (BF16OUT) {
            __hip_bfloat16* prow = preb + (size_t)gq * EMB + h * HD;
            #pragma unroll
            for (int k = 0; k < 4; ++k) prow[t + 8 * k] = __float2bfloat16(outv[k]);
        } else {
            float* prow = pre + (size_t)gq * EMB + h * HD;
            #pragma unroll
            for (int k = 0; k < 4; ++k) prow[t + 8 * k] = outv[k];
        }
    }
}

// ---------------- Kernel 3a: MFMA bf16 GEMM out = preb @ wob^T + bo + residual -------
__global__ __launch_bounds__(256) void k3_mfma(
    const __hip_bfloat16* __restrict__ preb, const __hip_bfloat16* __restrict__ wob,
    float* __restrict__ outp, const float* __restrict__ query,
    const float* __restrict__ bo)
{
    int w = threadIdx.x >> 6, lane = threadIdx.x & 63;
    size_t m0 = (size_t)blockIdx.x * 64;
    int n0 = w * 64;
    int lr = lane & 15, lg = lane >> 4;

    const short* pa = (const short*)preb;
    const short* pb = (const short*)wob;

    f32x4 acc[4][4];
    #pragma unroll
    for (int mt = 0; mt < 4; ++mt)
        #pragma unroll
        for (int nt = 0; nt < 4; ++nt) acc[mt][nt] = (f32x4){0.f, 0.f, 0.f, 0.f};

    #pragma unroll
    for (int k0 = 0; k0 < EMB; k0 += 32) {
        bf16x8 af[4], bf[4];
        #pragma unroll
        for (int mt = 0; mt < 4; ++mt)
            af[mt] = *(const bf16x8*)(pa + (m0 + mt * 16 + lr) * EMB + k0 + lg * 8);
        #pragma unroll
        for (int nt = 0; nt < 4; ++nt)
            bf[nt] = *(const bf16x8*)(pb + (size_t)(n0 + nt * 16 + lr) * EMB + k0 + lg * 8);
        #pragma unroll
        for (int mt = 0; mt < 4; ++mt)
            #pragma unroll
            for (int nt = 0; nt < 4; ++nt)
                acc[mt][nt] = __builtin_amdgcn_mfma_f32_16x16x32_bf16(
                    af[mt], bf[nt], acc[mt][nt], 0, 0, 0);
    }

    float bov[4];
    #pragma unroll
    for (int nt = 0; nt < 4; ++nt) bov[nt] = bo[n0 + nt * 16 + lr];

    #pragma unroll
    for (int mt = 0; mt < 4; ++mt)
        #pragma unroll
        for (int q = 0; q < 4; ++q) {
            size_t row = m0 + mt * 16 + lg * 4 + q;
            const float* qrow = query + row * EMB;
            float* orow = outp + row * EMB;
            #pragma unroll
            for (int nt = 0; nt < 4; ++nt) {
                int col = n0 + nt * 16 + lr;
                orow[col] = acc[mt][nt][q] + bov[nt] + qrow[col];
            }
        }
}

// ---------------- Kernel 3b: f32 fallback (in-place over d_out) ----------------------
__global__ __launch_bounds__(256) void k3_gemm(
    const float* __restrict__ pre, float* __restrict__ outp,
    const float* __restrict__ query, const float* __restrict__ Wo,
    const float* __restrict__ bo)
{
    __shared__ float As[64 * EMB];
    int tid = threadIdx.x;
    size_t r0 = (size_t)blockIdx.x * 64;
    {
        const float4* src = (const float4*)(pre + r0 * EMB);
        float4* dst = (float4*)As;
        for (int i = tid; i < 64 * EMB / 4; i += 256) dst[i] = src[i];
    }
    __syncthreads();

    int w = tid >> 6, lane = tid & 63;
    int rb = w * 16;
    float acc[16][4];
    #pragma unroll
    for (int r = 0; r < 16; ++r)
        #pragma unroll
        for (int j = 0; j < 4; ++j) acc[r][j] = 0.f;

    for (int kc = 0; kc < EMB / 4; ++kc) {
        float4 wreg[4];
        #pragma unroll
        for (int j = 0; j < 4; ++j)
            wreg[j] = *(const float4*)&Wo[(size_t)(lane + 64 * j) * EMB + kc * 4];
        #pragma unroll
        for (int r = 0; r < 16; ++r) {
            float4 a = *(const float4*)&As[(rb + r) * EMB + kc * 4];
            #pragma unroll
            for (int j = 0; j < 4; ++j)
                acc[r][j] += a.x * wreg[j].x + a.y * wreg[j].y
                           + a.z * wreg[j].z + a.w * wreg[j].w;
        }
    }

    #pragma unroll
    for (int r = 0; r < 16; ++r) {
        size_t row = r0 + rb + r;
        #pragma unroll
        for (int j = 0; j < 4; ++j) {
            int c = lane + 64 * j;
            outp[row * EMB + c] = acc[r][j] + bo[c] + query[row * EMB + c];
        }
    }
}

extern "C" void kernel_launch(void* const* d_in, const int* in_sizes, int n_in,
                              void* d_out, int out_size, void* d_ws, size_t ws_size,
                              hipStream_t stream) {
    const float* query = (const float*)d_in[0];
    const float* key   = (const float*)d_in[1];
    const float* value = (const float*)d_in[2];
    const float* refp  = (const float*)d_in[3];
    const float* Wq   = (const float*)d_in[4];
    const float* bq   = (const float*)d_in[5];
    const float* Wk   = (const float*)d_in[6];
    const float* bk   = (const float*)d_in[7];
    const float* Wv   = (const float*)d_in[8];
    const float* bv   = (const float*)d_in[9];
    const float* Woff = (const float*)d_in[10];
    const float* boff = (const float*)d_in[11];
    const float* Wo   = (const float*)d_in[12];
    const float* bo   = (const float*)d_in[13];
    (void)in_sizes; (void)n_in; (void)out_size;

    float* out = (float*)d_out;
    char*  ws  = (char*)d_ws;
    float* kk  = (float*)(ws + KK_OFF);

    k1_keys<<<BS * NH, 64, 0, stream>>>(query, key, refp, Woff, boff, Wk, bk, kk);

    if (ws_size >= WS_NEEDED) {
        __hip_bfloat16* wob  = (__hip_bfloat16*)(ws + WOB_OFF);
        __hip_bfloat16* preb = (__hip_bfloat16*)(ws + PREB_OFF);
        kconv_wo<<<EMB * EMB / 1024, 256, 0, stream>>>(Wo, wob);
        k2_main<1><<<BS * NQ / 4, 256, 0, stream>>>(query, value, refp, Wq, bq, Wv, bv,
                                                    Woff, boff, kk, nullptr, preb);
        k3_mfma<<<BS * NQ / 64, 256, 0, stream>>>(preb, wob, out, query, bo);
    } else {
        k2_main<0><<<BS * NQ / 4, 256, 0, stream>>>(query, value, refp, Wq, bq, Wv, bv,
                                                    Woff, boff, kk, out, nullptr);
        k3_gemm<<<BS * NQ / 64, 256, 0, stream>>>(out, out, query, Wo, bo);
    }
}

// Round 5
// 93.527 us; speedup vs baseline: 5.7776x; 1.2841x over previous
//
#include <hip/hip_runtime.h>
#include <hip/hip_bf16.h>
#include <math.h>

#define NH   8
#define HD   32
#define NP   4
#define EMB  256
#define IMG_H 100
#define IMG_W 100
#define NQ   10000
#define NV   10000
#define BS   4

#define W4S 36   // padded stride for 32-wide rows: bank (4*row+col)%32, conflict-free

#define FENCE() asm volatile("" ::: "memory")

typedef __attribute__((ext_vector_type(8))) short bf16x8;
typedef __attribute__((ext_vector_type(4))) float f32x4;

// ---- ws layout ----------------------------------------------------------------------
#define KT_OFF    0                                   // kt  [BS][NP][NH][HD] f32 16 KB
#define KB_OFF    16384                               // kb  [BS][NP][NH]     f32 512 B
#define BO2_OFF   17408                               // bo2 [EMB]            f32 1 KB
#define WCF_OFF   18432                               // Wcomb f32 [EMB][EMB] 256 KB
#define WCB_OFF   (18432 + 262144)                    // Wcomb bf16           128 KB
#define PREB_OFF  (18432 + 262144 + 131072)           // pre bf16 [BS*NQ][EMB] 20.48 MB
#define WS_MIN    ((size_t)PREB_OFF)
#define WS_FULL   ((size_t)PREB_OFF + (size_t)BS * NQ * EMB * 2)

// ---------------- Kernel 1: sampled keys -> kt = Wq^T(Wk s + bk), kb = bq.(Wk s + bk) -
__global__ __launch_bounds__(64) void k1_keys(
    const float* __restrict__ query, const float* __restrict__ key,
    const float* __restrict__ refp,  const float* __restrict__ Woff,
    const float* __restrict__ boff,  const float* __restrict__ Wk,
    const float* __restrict__ bk,    const float* __restrict__ Wq,
    const float* __restrict__ bq,
    float* __restrict__ kt, float* __restrict__ kb)
{
    int b = blockIdx.x >> 3, h = blockIdx.x & 7;
    __shared__ float q0[HD];
    __shared__ float off[8];
    __shared__ float ks[NP][HD];
    __shared__ float kkl[NP][HD];
    int l = threadIdx.x;

    if (l < HD) q0[l] = query[(size_t)(b * NQ) * EMB + h * HD + l];
    __syncthreads();

    if (l < 8) {
        float s = boff[l];
        #pragma unroll
        for (int d = 0; d < HD; ++d) s += q0[d] * Woff[l * HD + d];
        off[l] = s;
    }
    __syncthreads();

    if (l < HD) {
        float refx = refp[(size_t)(b * NQ) * 2 + 0];
        float refy = refp[(size_t)(b * NQ) * 2 + 1];
        for (int p = 0; p < NP; ++p) {
            float x = refx * IMG_W + off[p * 2 + 0] - 0.5f;
            float y = refy * IMG_H + off[p * 2 + 1] - 0.5f;
            float x0f = floorf(x), y0f = floorf(y);
            int ix0 = (int)x0f, iy0 = (int)y0f;
            float fx = x - x0f, fy = y - y0f;
            float acc = 0.f;
            #pragma unroll
            for (int cy = 0; cy < 2; ++cy)
                #pragma unroll
                for (int cx = 0; cx < 2; ++cx) {
                    int xi = ix0 + cx, yi = iy0 + cy;
                    if ((unsigned)xi < IMG_W && (unsigned)yi < IMG_H) {
                        float wgt = (cx ? fx : 1.f - fx) * (cy ? fy : 1.f - fy);
                        acc += wgt * key[((size_t)b * NV + yi * IMG_W + xi) * EMB + h * HD + l];
                    }
                }
            ks[p][l] = acc;
        }
    }
    __syncthreads();

    // kkl = Wk . ks + bk
    #pragma unroll
    for (int t = 0; t < 2; ++t) {
        int idx = l + 64 * t;
        int p = idx >> 5, dout = idx & 31;
        float s = bk[dout];
        #pragma unroll
        for (int d = 0; d < HD; ++d) s += Wk[dout * HD + d] * ks[p][d];
        kkl[p][dout] = s;
    }
    __syncthreads();

    // kt[p][d] = sum_dd Wq[dd][d] * kkl[p][dd]
    #pragma unroll
    for (int t = 0; t < 2; ++t) {
        int idx = l + 64 * t;
        int p = idx >> 5, d = idx & 31;
        float s = 0.f;
        #pragma unroll
        for (int dd = 0; dd < HD; ++dd) s += Wq[dd * HD + d] * kkl[p][dd];
        kt[((b * NP + p) * NH + h) * HD + d] = s;
    }
    if (l < NP) {
        float s = 0.f;
        #pragma unroll
        for (int dd = 0; dd < HD; ++dd) s += bq[dd] * kkl[l][dd];
        kb[(b * NP + l) * NH + h] = s;
    }
}

// ---------------- Kernel: fold Wv into Wo -> Wcomb (f32 + bf16), bo2 -----------------
__global__ __launch_bounds__(256) void kcomb(
    const float* __restrict__ Wo, const float* __restrict__ Wv,
    const float* __restrict__ bv, const float* __restrict__ bo,
    float* __restrict__ wcf, __hip_bfloat16* __restrict__ wcb,
    float* __restrict__ bo2)
{
    __shared__ float sWv[HD * HD];   // [dd][d]
    __shared__ float sWoR[EMB];
    __shared__ float sws[4];
    int e = blockIdx.x, col = threadIdx.x;
    *(float4*)&sWv[col * 4] = *(const float4*)(Wv + col * 4);
    sWoR[col] = Wo[(size_t)e * EMB + col];
    __syncthreads();

    int h = col >> 5, d = col & 31;
    float s = 0.f;
    #pragma unroll
    for (int dd = 0; dd < HD; ++dd) s += sWoR[h * HD + dd] * sWv[dd * HD + d];
    wcf[(size_t)e * EMB + col] = s;
    wcb[(size_t)e * EMB + col] = __float2bfloat16(s);

    float pb = bv[d] * sWoR[col];
    #pragma unroll
    for (int o = 1; o < 64; o <<= 1) pb += __shfl_xor(pb, o);
    if ((col & 63) == 0) sws[col >> 6] = pb;
    __syncthreads();
    if (col == 0) bo2[e] = bo[e] + sws[0] + sws[1] + sws[2] + sws[3];
}

// ---------------- Kernel 2: per-query pipeline (no dense projections) ----------------
template<int BF16OUT>
__global__ __launch_bounds__(256) void k2_main(
    const float* __restrict__ query, const float* __restrict__ value,
    const float* __restrict__ refp,
    const float* __restrict__ Woff, const float* __restrict__ boff,
    const float* __restrict__ kt, const float* __restrict__ kb,
    float* __restrict__ pre, __hip_bfloat16* __restrict__ preb)
{
    __shared__ float sWoff[8 * W4S];
    __shared__ float sboff[8];
    __shared__ float skt[NP * NH * W4S];     // padded: bank(4*(p*8+h)+d), conflict-free
    __shared__ float skb[NP * NH];
    __shared__ float qld[4][NH * W4S];
    __shared__ float offs[4][64];
    __shared__ float attnw[4][32];
    __shared__ int   soff4[4][32][4];
    __shared__ float swgt4[4][32][4];

    int tid = threadIdx.x;
    int b0 = (blockIdx.x * 4) / NQ;          // uniform across block (4 | NQ)

    for (int i = tid; i < 8 * HD; i += 256) sWoff[(i >> 5) * W4S + (i & 31)] = Woff[i];
    if (tid < 8)  sboff[tid] = boff[tid];
    {   // kt: 1024 floats -> padded rows
        int j = tid * 4;
        *(float4*)&skt[(j >> 5) * W4S + (j & 31)] =
            *(const float4*)(kt + b0 * (NP * NH * HD) + j);
    }
    if (tid < NP * NH) skb[tid] = kb[b0 * (NP * NH) + tid];

    int w = tid >> 6, lane = tid & 63;
    int gq = blockIdx.x * 4 + w;
    int b = b0;

    float4 qv = *(const float4*)(query + (size_t)gq * EMB + lane * 4);
    { int e = lane * 4; *(float4*)&qld[w][(e >> 5) * W4S + (e & 31)] = qv; }
    float refx = refp[(size_t)gq * 2 + 0];
    float refy = refp[(size_t)gq * 2 + 1];
    __syncthreads();

    int h = lane >> 3, t = lane & 7;

    // register-cache q[h,:]
    float qr[HD];
    #pragma unroll
    for (int d = 0; d < HD; d += 4) {
        float4 v4 = *(const float4*)&qld[w][h * W4S + d];
        qr[d] = v4.x; qr[d + 1] = v4.y; qr[d + 2] = v4.z; qr[d + 3] = v4.w;
    }

    // sampling offsets: lane (h, j=t)
    {
        float s = sboff[t];
        const float* wr = &sWoff[t * W4S];
        #pragma unroll
        for (int d = 0; d < HD; d += 4) {
            float4 ww = *(const float4*)(wr + d);
            s += qr[d] * ww.x + qr[d+1] * ww.y + qr[d+2] * ww.z + qr[d+3] * ww.w;
        }
        offs[w][h * 8 + t] = s;
    }

    // logits via folded keys: plog[p] = q . kt[p,h,:] + kb[p,h]
    float plog[NP];
    #pragma unroll
    for (int p = 0; p < NP; ++p) {
        const float* kr = &skt[(p * NH + h) * W4S];
        float s = 0.f;
        #pragma unroll
        for (int k = 0; k < 4; ++k) s += qr[t + 8 * k] * kr[t + 8 * k];
        plog[p] = s;
    }
    #pragma unroll
    for (int p = 0; p < NP; ++p) {
        plog[p] += __shfl_xor(plog[p], 1, 8);
        plog[p] += __shfl_xor(plog[p], 2, 8);
        plog[p] += __shfl_xor(plog[p], 4, 8);
        plog[p] += skb[p * NH + h];
    }
    {
        float mm = fmaxf(fmaxf(plog[0], plog[1]), fmaxf(plog[2], plog[3]));
        float e0 = __expf(plog[0] - mm), e1 = __expf(plog[1] - mm);
        float e2 = __expf(plog[2] - mm), e3 = __expf(plog[3] - mm);
        float inv = 1.f / (e0 + e1 + e2 + e3);
        if (t < 4) {
            float a = (t == 0) ? e0 : (t == 1) ? e1 : (t == 2) ? e2 : e3;
            attnw[w][h * 4 + t] = a * inv;
        }
    }
    FENCE();

    // metadata: one (h2,p) per lane<32 — premultiplied weights + element offsets
    if (lane < 32) {
        int h2 = lane >> 2, p = lane & 3;
        float x = refx * IMG_W + offs[w][h2 * 8 + p * 2 + 0] - 0.5f;
        float y = refy * IMG_H + offs[w][h2 * 8 + p * 2 + 1] - 0.5f;
        float x0f = floorf(x), y0f = floorf(y);
        int ix0 = (int)x0f, iy0 = (int)y0f;
        float fx = x - x0f, fy = y - y0f;
        float aw = attnw[w][lane];
        float wx1 = fx * aw, wx0 = aw - wx1;
        int bbase = b * (NV * EMB) + h2 * HD;
        int   o4[4]; float g4[4];
        #pragma unroll
        for (int c = 0; c < 4; ++c) {
            int cx = c & 1, cy = c >> 1;
            int xi = ix0 + cx, yi = iy0 + cy;
            bool valid = ((unsigned)xi < IMG_W) & ((unsigned)yi < IMG_H);
            int xc = min(max(xi, 0), IMG_W - 1);
            int yc = min(max(yi, 0), IMG_H - 1);
            o4[c] = bbase + (yc * IMG_W + xc) * EMB;
            float wv = (cx ? wx1 : wx0) * (cy ? fy : 1.f - fy);
            g4[c] = valid ? wv : 0.f;
        }
        int4   ov = {o4[0], o4[1], o4[2], o4[3]};
        float4 gv = {g4[0], g4[1], g4[2], g4[3]};
        *(int4*)&soff4[w][lane][0]   = ov;
        *(float4*)&swgt4[w][lane][0] = gv;
    }
    FENCE();

    // gather + weighted sum -> store aggregate row directly (Wv folded into k3)
    {
        int half = lane >> 5, dcol = lane & 31;
        #pragma unroll
        for (int i = 0; i < 4; ++i) {
            int hh = i * 2 + half;
            float vals[16], wv[16];
            #pragma unroll
            for (int p = 0; p < NP; ++p) {
                int hp = hh * 4 + p;
                int4   o4 = *(const int4*)&soff4[w][hp][0];
                float4 g4 = *(const float4*)&swgt4[w][hp][0];
                vals[p*4+0] = value[(unsigned)(o4.x + dcol)];
                vals[p*4+1] = value[(unsigned)(o4.y + dcol)];
                vals[p*4+2] = value[(unsigned)(o4.z + dcol)];
                vals[p*4+3] = value[(unsigned)(o4.w + dcol)];
                wv[p*4+0] = g4.x; wv[p*4+1] = g4.y; wv[p*4+2] = g4.z; wv[p*4+3] = g4.w;
            }
            float acc = 0.f;
            #pragma unroll
            for (int u = 0; u < 16; ++u) acc += wv[u] * vals[u];
            if (BF16OUT)
                preb[(size_t)gq * EMB + hh * HD + dcol] = __float2bfloat16(acc);
            else
                pre[(size_t)gq * EMB + hh * HD + dcol] = acc;
        }
    }
}

// ---------------- Kernel 3a: MFMA bf16 GEMM out = preb @ Wcomb^T + bo2 + residual ----
__global__ __launch_bounds__(256) void k3_mfma(
    const __hip_bfloat16* __restrict__ preb, const __hip_bfloat16* __restrict__ wcb,
    float* __restrict__ outp, const float* __restrict__ query,
    const float* __restrict__ bo2)
{
    int w = threadIdx.x >> 6, lane = threadIdx.x & 63;
    size_t m0 = (size_t)blockIdx.x * 64;
    int n0 = w * 64;
    int lr = lane & 15, lg = lane >> 4;

    const short* pa = (const short*)preb;
    const short* pb = (const short*)wcb;

    f32x4 acc[4][4];
    #pragma unroll
    for (int mt = 0; mt < 4; ++mt)
        #pragma unroll
        for (int nt = 0; nt < 4; ++nt) acc[mt][nt] = (f32x4){0.f, 0.f, 0.f, 0.f};

    #pragma unroll
    for (int k0 = 0; k0 < EMB; k0 += 32) {
        bf16x8 af[4], bf[4];
        #pragma unroll
        for (int mt = 0; mt < 4; ++mt)
            af[mt] = *(const bf16x8*)(pa + (m0 + mt * 16 + lr) * EMB + k0 + lg * 8);
        #pragma unroll
        for (int nt = 0; nt < 4; ++nt)
            bf[nt] = *(const bf16x8*)(pb + (size_t)(n0 + nt * 16 + lr) * EMB + k0 + lg * 8);
        #pragma unroll
        for (int mt = 0; mt < 4; ++mt)
            #pragma unroll
            for (int nt = 0; nt < 4; ++nt)
                acc[mt][nt] = __builtin_amdgcn_mfma_f32_16x16x32_bf16(
                    af[mt], bf[nt], acc[mt][nt], 0, 0, 0);
    }

    float bov[4];
    #pragma unroll
    for (int nt = 0; nt < 4; ++nt) bov[nt] = bo2[n0 + nt * 16 + lr];

    #pragma unroll
    for (int mt = 0; mt < 4; ++mt)
        #pragma unroll
        for (int q = 0; q < 4; ++q) {
            size_t row = m0 + mt * 16 + lg * 4 + q;
            const float* qrow = query + row * EMB;
            float* orow = outp + row * EMB;
            #pragma unroll
            for (int nt = 0; nt < 4; ++nt) {
                int col = n0 + nt * 16 + lr;
                orow[col] = acc[mt][nt][q] + bov[nt] + qrow[col];
            }
        }
}

// ---------------- Kernel 3b: f32 fallback (in-place over d_out, Wcomb f32) -----------
__global__ __launch_bounds__(256) void k3_gemm(
    const float* __restrict__ pre, float* __restrict__ outp,
    const float* __restrict__ query, const float* __restrict__ wcf,
    const float* __restrict__ bo2)
{
    __shared__ float As[64 * EMB];
    int tid = threadIdx.x;
    size_t r0 = (size_t)blockIdx.x * 64;
    {
        const float4* src = (const float4*)(pre + r0 * EMB);
        float4* dst = (float4*)As;
        for (int i = tid; i < 64 * EMB / 4; i += 256) dst[i] = src[i];
    }
    __syncthreads();

    int w = tid >> 6, lane = tid & 63;
    int rb = w * 16;
    float acc[16][4];
    #pragma unroll
    for (int r = 0; r < 16; ++r)
        #pragma unroll
        for (int j = 0; j < 4; ++j) acc[r][j] = 0.f;

    for (int kc = 0; kc < EMB / 4; ++kc) {
        float4 wreg[4];
        #pragma unroll
        for (int j = 0; j < 4; ++j)
            wreg[j] = *(const float4*)&wcf[(size_t)(lane + 64 * j) * EMB + kc * 4];
        #pragma unroll
        for (int r = 0; r < 16; ++r) {
            float4 a = *(const float4*)&As[(rb + r) * EMB + kc * 4];
            #pragma unroll
            for (int j = 0; j < 4; ++j)
                acc[r][j] += a.x * wreg[j].x + a.y * wreg[j].y
                           + a.z * wreg[j].z + a.w * wreg[j].w;
        }
    }

    #pragma unroll
    for (int r = 0; r < 16; ++r) {
        size_t row = r0 + rb + r;
        #pragma unroll
        for (int j = 0; j < 4; ++j) {
            int c = lane + 64 * j;
            outp[row * EMB + c] = acc[r][j] + bo2[c] + query[row * EMB + c];
        }
    }
}

extern "C" void kernel_launch(void* const* d_in, const int* in_sizes, int n_in,
                              void* d_out, int out_size, void* d_ws, size_t ws_size,
                              hipStream_t stream) {
    const float* query = (const float*)d_in[0];
    const float* key   = (const float*)d_in[1];
    const float* value = (const float*)d_in[2];
    const float* refp  = (const float*)d_in[3];
    const float* Wq   = (const float*)d_in[4];
    const float* bq   = (const float*)d_in[5];
    const float* Wk   = (const float*)d_in[6];
    const float* bk   = (const float*)d_in[7];
    const float* Wv   = (const float*)d_in[8];
    const float* bv   = (const float*)d_in[9];
    const float* Woff = (const float*)d_in[10];
    const float* boff = (const float*)d_in[11];
    const float* Wo   = (const float*)d_in[12];
    const float* bo   = (const float*)d_in[13];
    (void)in_sizes; (void)n_in; (void)out_size;

    float* out = (float*)d_out;
    char*  ws  = (char*)d_ws;
    float* kt  = (float*)(ws + KT_OFF);
    float* kb  = (float*)(ws + KB_OFF);
    float* bo2 = (float*)(ws + BO2_OFF);
    float* wcf = (float*)(ws + WCF_OFF);
    __hip_bfloat16* wcb = (__hip_bfloat16*)(ws + WCB_OFF);

    k1_keys<<<BS * NH, 64, 0, stream>>>(query, key, refp, Woff, boff, Wk, bk,
                                        Wq, bq, kt, kb);
    kcomb<<<EMB, 256, 0, stream>>>(Wo, Wv, bv, bo, wcf, wcb, bo2);

    if (ws_size >= WS_FULL) {
        __hip_bfloat16* preb = (__hip_bfloat16*)(ws + PREB_OFF);
        k2_main<1><<<BS * NQ / 4, 256, 0, stream>>>(query, value, refp, Woff, boff,
                                                    kt, kb, nullptr, preb);
        k3_mfma<<<BS * NQ / 64, 256, 0, stream>>>(preb, wcb, out, query, bo2);
    } else {
        // agg f32 staged in d_out; k3 re-reads own rows through LDS then overwrites
        k2_main<0><<<BS * NQ / 4, 256, 0, stream>>>(query, value, refp, Woff, boff,
                                                    kt, kb, out, nullptr);
        k3_gemm<<<BS * NQ / 64, 256, 0, stream>>>(out, out, query, wcf, bo2);
    }
}

// Round 6
// 88.288 us; speedup vs baseline: 6.1204x; 1.0593x over previous
//
#include <hip/hip_runtime.h>
#include <hip/hip_bf16.h>
#include <math.h>

#define NH   8
#define HD   32
#define NP   4
#define EMB  256
#define IMG_H 100
#define IMG_W 100
#define NQ   10000
#define NV   10000
#define BS   4

#define W4S 36   // padded stride for 32-wide rows

#define FENCE() asm volatile("" ::: "memory")

typedef __attribute__((ext_vector_type(8))) short bf16x8;
typedef __attribute__((ext_vector_type(4))) float f32x4;

// ---- ws layout ----------------------------------------------------------------------
#define KT_OFF    0                                   // kt  [BS][NP][NH][HD] f32 16 KB
#define KB_OFF    16384                               // kb  [BS][NP][NH]     f32 512 B
#define BO2_OFF   17408                               // bo2 [EMB]            f32 1 KB
#define WCF_OFF   18432                               // Wcomb f32 [EMB][EMB] 256 KB
#define WCB_OFF   (18432 + 262144)                    // Wcomb bf16           128 KB
#define PREB_OFF  (18432 + 262144 + 131072)           // pre bf16 [BS*NQ][EMB] 20.48 MB
#define WS_FULL   ((size_t)PREB_OFF + (size_t)BS * NQ * EMB * 2)

// ---------------- Kernel 1: sampled keys -> kt = Wq^T(Wk s + bk), kb = bq.(Wk s + bk) -
__global__ __launch_bounds__(64) void k1_keys(
    const float* __restrict__ query, const float* __restrict__ key,
    const float* __restrict__ refp,  const float* __restrict__ Woff,
    const float* __restrict__ boff,  const float* __restrict__ Wk,
    const float* __restrict__ bk,    const float* __restrict__ Wq,
    const float* __restrict__ bq,
    float* __restrict__ kt, float* __restrict__ kb)
{
    int b = blockIdx.x >> 3, h = blockIdx.x & 7;
    __shared__ float q0[HD];
    __shared__ float off[8];
    __shared__ float ks[NP][HD];
    __shared__ float kkl[NP][HD];
    int l = threadIdx.x;

    if (l < HD) q0[l] = query[(size_t)(b * NQ) * EMB + h * HD + l];
    __syncthreads();

    if (l < 8) {
        float s = boff[l];
        #pragma unroll
        for (int d = 0; d < HD; ++d) s += q0[d] * Woff[l * HD + d];
        off[l] = s;
    }
    __syncthreads();

    if (l < HD) {
        float refx = refp[(size_t)(b * NQ) * 2 + 0];
        float refy = refp[(size_t)(b * NQ) * 2 + 1];
        for (int p = 0; p < NP; ++p) {
            float x = refx * IMG_W + off[p * 2 + 0] - 0.5f;
            float y = refy * IMG_H + off[p * 2 + 1] - 0.5f;
            float x0f = floorf(x), y0f = floorf(y);
            int ix0 = (int)x0f, iy0 = (int)y0f;
            float fx = x - x0f, fy = y - y0f;
            float acc = 0.f;
            #pragma unroll
            for (int cy = 0; cy < 2; ++cy)
                #pragma unroll
                for (int cx = 0; cx < 2; ++cx) {
                    int xi = ix0 + cx, yi = iy0 + cy;
                    if ((unsigned)xi < IMG_W && (unsigned)yi < IMG_H) {
                        float wgt = (cx ? fx : 1.f - fx) * (cy ? fy : 1.f - fy);
                        acc += wgt * key[((size_t)b * NV + yi * IMG_W + xi) * EMB + h * HD + l];
                    }
                }
            ks[p][l] = acc;
        }
    }
    __syncthreads();

    #pragma unroll
    for (int t = 0; t < 2; ++t) {
        int idx = l + 64 * t;
        int p = idx >> 5, dout = idx & 31;
        float s = bk[dout];
        #pragma unroll
        for (int d = 0; d < HD; ++d) s += Wk[dout * HD + d] * ks[p][d];
        kkl[p][dout] = s;
    }
    __syncthreads();

    #pragma unroll
    for (int t = 0; t < 2; ++t) {
        int idx = l + 64 * t;
        int p = idx >> 5, d = idx & 31;
        float s = 0.f;
        #pragma unroll
        for (int dd = 0; dd < HD; ++dd) s += Wq[dd * HD + d] * kkl[p][dd];
        kt[((b * NP + p) * NH + h) * HD + d] = s;
    }
    if (l < NP) {
        float s = 0.f;
        #pragma unroll
        for (int dd = 0; dd < HD; ++dd) s += bq[dd] * kkl[l][dd];
        kb[(b * NP + l) * NH + h] = s;
    }
}

// ---------------- Kernel: fold Wv into Wo -> Wcomb (f32 + bf16), bo2 -----------------
__global__ __launch_bounds__(256) void kcomb(
    const float* __restrict__ Wo, const float* __restrict__ Wv,
    const float* __restrict__ bv, const float* __restrict__ bo,
    float* __restrict__ wcf, __hip_bfloat16* __restrict__ wcb,
    float* __restrict__ bo2)
{
    __shared__ float sWv[HD * HD];   // [dd][d]
    __shared__ float sWoR[EMB];
    __shared__ float sws[4];
    int e = blockIdx.x, col = threadIdx.x;
    *(float4*)&sWv[col * 4] = *(const float4*)(Wv + col * 4);
    sWoR[col] = Wo[(size_t)e * EMB + col];
    __syncthreads();

    int h = col >> 5, d = col & 31;
    float s = 0.f;
    #pragma unroll
    for (int dd = 0; dd < HD; ++dd) s += sWoR[h * HD + dd] * sWv[dd * HD + d];
    wcf[(size_t)e * EMB + col] = s;
    wcb[(size_t)e * EMB + col] = __float2bfloat16(s);

    float pb = bv[d] * sWoR[col];
    #pragma unroll
    for (int o = 1; o < 64; o <<= 1) pb += __shfl_xor(pb, o);
    if ((col & 63) == 0) sws[col >> 6] = pb;
    __syncthreads();
    if (col == 0) bo2[e] = bo[e] + sws[0] + sws[1] + sws[2] + sws[3];
}

// ---------------- Kernel 2: per-query pipeline, float4 gather ------------------------
template<int BF16OUT>
__global__ __launch_bounds__(256) void k2_main(
    const float* __restrict__ query, const float* __restrict__ value,
    const float* __restrict__ refp,
    const float* __restrict__ Woff, const float* __restrict__ boff,
    const float* __restrict__ kt, const float* __restrict__ kb,
    float* __restrict__ pre, __hip_bfloat16* __restrict__ preb)
{
    __shared__ float sWoff[8 * W4S];
    __shared__ float sboff[8];
    __shared__ float skt[NP * NH * W4S];
    __shared__ float skb[NP * NH];
    __shared__ float qld[4][NH * W4S];
    __shared__ float offs[4][64];
    __shared__ float attnw[4][32];
    __shared__ int   soff4[4][32][4];
    __shared__ float swgt4[4][32][4];

    int tid = threadIdx.x;
    int b0 = (blockIdx.x * 4) / NQ;          // uniform across block (4 | NQ)

    for (int i = tid; i < 8 * HD; i += 256) sWoff[(i >> 5) * W4S + (i & 31)] = Woff[i];
    if (tid < 8)  sboff[tid] = boff[tid];
    {
        int j = tid * 4;
        *(float4*)&skt[(j >> 5) * W4S + (j & 31)] =
            *(const float4*)(kt + b0 * (NP * NH * HD) + j);
    }
    if (tid < NP * NH) skb[tid] = kb[b0 * (NP * NH) + tid];

    int w = tid >> 6, lane = tid & 63;
    int gq = blockIdx.x * 4 + w;
    int b = b0;

    float4 qv = *(const float4*)(query + (size_t)gq * EMB + lane * 4);
    { int e = lane * 4; *(float4*)&qld[w][(e >> 5) * W4S + (e & 31)] = qv; }
    float refx = refp[(size_t)gq * 2 + 0];
    float refy = refp[(size_t)gq * 2 + 1];
    __syncthreads();

    int h = lane >> 3, t = lane & 7;

    // register-cache q[h,:]
    float qr[HD];
    #pragma unroll
    for (int d = 0; d < HD; d += 4) {
        float4 v4 = *(const float4*)&qld[w][h * W4S + d];
        qr[d] = v4.x; qr[d + 1] = v4.y; qr[d + 2] = v4.z; qr[d + 3] = v4.w;
    }

    // sampling offsets: lane (h, j=t)
    {
        float s = sboff[t];
        const float* wr = &sWoff[t * W4S];
        #pragma unroll
        for (int d = 0; d < HD; d += 4) {
            float4 ww = *(const float4*)(wr + d);
            s += qr[d] * ww.x + qr[d+1] * ww.y + qr[d+2] * ww.z + qr[d+3] * ww.w;
        }
        offs[w][h * 8 + t] = s;
    }

    // logits via folded keys: plog[p] = q . kt[p,h,:] + kb[p,h]
    float plog[NP];
    #pragma unroll
    for (int p = 0; p < NP; ++p) {
        const float* kr = &skt[(p * NH + h) * W4S];
        float s = 0.f;
        #pragma unroll
        for (int k = 0; k < 4; ++k) s += qr[t + 8 * k] * kr[t + 8 * k];
        plog[p] = s;
    }
    #pragma unroll
    for (int p = 0; p < NP; ++p) {
        plog[p] += __shfl_xor(plog[p], 1, 8);
        plog[p] += __shfl_xor(plog[p], 2, 8);
        plog[p] += __shfl_xor(plog[p], 4, 8);
        plog[p] += skb[p * NH + h];
    }
    {
        float mm = fmaxf(fmaxf(plog[0], plog[1]), fmaxf(plog[2], plog[3]));
        float e0 = __expf(plog[0] - mm), e1 = __expf(plog[1] - mm);
        float e2 = __expf(plog[2] - mm), e3 = __expf(plog[3] - mm);
        float inv = 1.f / (e0 + e1 + e2 + e3);
        if (t < 4) {
            float a = (t == 0) ? e0 : (t == 1) ? e1 : (t == 2) ? e2 : e3;
            attnw[w][h * 4 + t] = a * inv;
        }
    }
    FENCE();

    // metadata: one (h2,p) per lane<32 — premultiplied weights + element offsets
    if (lane < 32) {
        int h2 = lane >> 2, p = lane & 3;
        float x = refx * IMG_W + offs[w][h2 * 8 + p * 2 + 0] - 0.5f;
        float y = refy * IMG_H + offs[w][h2 * 8 + p * 2 + 1] - 0.5f;
        float x0f = floorf(x), y0f = floorf(y);
        int ix0 = (int)x0f, iy0 = (int)y0f;
        float fx = x - x0f, fy = y - y0f;
        float aw = attnw[w][lane];
        float wx1 = fx * aw, wx0 = aw - wx1;
        int bbase = b * (NV * EMB) + h2 * HD;
        int   o4[4]; float g4[4];
        #pragma unroll
        for (int c = 0; c < 4; ++c) {
            int cx = c & 1, cy = c >> 1;
            int xi = ix0 + cx, yi = iy0 + cy;
            bool valid = ((unsigned)xi < IMG_W) & ((unsigned)yi < IMG_H);
            int xc = min(max(xi, 0), IMG_W - 1);
            int yc = min(max(yi, 0), IMG_H - 1);
            o4[c] = bbase + (yc * IMG_W + xc) * EMB;
            float wv = (cx ? wx1 : wx0) * (cy ? fy : 1.f - fy);
            g4[c] = valid ? wv : 0.f;
        }
        int4   ov = {o4[0], o4[1], o4[2], o4[3]};
        float4 gv = {g4[0], g4[1], g4[2], g4[3]};
        *(int4*)&soff4[w][lane][0]   = ov;
        *(float4*)&swgt4[w][lane][0] = gv;
    }
    FENCE();

    // gather: lane = (head hh, channel-group cg); 16 float4 loads, 64 FMA
    {
        int hh = lane >> 3, cg = lane & 7;
        int cb = cg * 4;
        float4 acc = {0.f, 0.f, 0.f, 0.f};
        #pragma unroll
        for (int p = 0; p < NP; ++p) {
            int hp = hh * 4 + p;
            int4   o4 = *(const int4*)&soff4[w][hp][0];
            float4 g4 = *(const float4*)&swgt4[w][hp][0];
            float4 v0 = *(const float4*)(value + (unsigned)(o4.x + cb));
            float4 v1 = *(const float4*)(value + (unsigned)(o4.y + cb));
            float4 v2 = *(const float4*)(value + (unsigned)(o4.z + cb));
            float4 v3 = *(const float4*)(value + (unsigned)(o4.w + cb));
            acc.x += g4.x * v0.x + g4.y * v1.x + g4.z * v2.x + g4.w * v3.x;
            acc.y += g4.x * v0.y + g4.y * v1.y + g4.z * v2.y + g4.w * v3.y;
            acc.z += g4.x * v0.z + g4.y * v1.z + g4.z * v2.z + g4.w * v3.z;
            acc.w += g4.x * v0.w + g4.y * v1.w + g4.z * v2.w + g4.w * v3.w;
        }
        if (BF16OUT) {
            __hip_bfloat16 b4[4];
            b4[0] = __float2bfloat16(acc.x);
            b4[1] = __float2bfloat16(acc.y);
            b4[2] = __float2bfloat16(acc.z);
            b4[3] = __float2bfloat16(acc.w);
            ushort4 pk;
            pk.x = *reinterpret_cast<unsigned short*>(&b4[0]);
            pk.y = *reinterpret_cast<unsigned short*>(&b4[1]);
            pk.z = *reinterpret_cast<unsigned short*>(&b4[2]);
            pk.w = *reinterpret_cast<unsigned short*>(&b4[3]);
            *(ushort4*)((unsigned short*)preb + (size_t)gq * EMB + hh * HD + cb) = pk;
        } else {
            *(float4*)(pre + (size_t)gq * EMB + hh * HD + cb) = acc;
        }
    }
}

// ---------------- Kernel 3a: MFMA bf16 GEMM out = preb @ Wcomb^T + bo2 + residual ----
__global__ __launch_bounds__(256) void k3_mfma(
    const __hip_bfloat16* __restrict__ preb, const __hip_bfloat16* __restrict__ wcb,
    float* __restrict__ outp, const float* __restrict__ query,
    const float* __restrict__ bo2)
{
    int w = threadIdx.x >> 6, lane = threadIdx.x & 63;
    size_t m0 = (size_t)blockIdx.x * 64;
    int n0 = w * 64;
    int lr = lane & 15, lg = lane >> 4;

    const short* pa = (const short*)preb;
    const short* pb = (const short*)wcb;

    f32x4 acc[4][4];
    #pragma unroll
    for (int mt = 0; mt < 4; ++mt)
        #pragma unroll
        for (int nt = 0; nt < 4; ++nt) acc[mt][nt] = (f32x4){0.f, 0.f, 0.f, 0.f};

    #pragma unroll
    for (int k0 = 0; k0 < EMB; k0 += 32) {
        bf16x8 af[4], bf[4];
        #pragma unroll
        for (int mt = 0; mt < 4; ++mt)
            af[mt] = *(const bf16x8*)(pa + (m0 + mt * 16 + lr) * EMB + k0 + lg * 8);
        #pragma unroll
        for (int nt = 0; nt < 4; ++nt)
            bf[nt] = *(const bf16x8*)(pb + (size_t)(n0 + nt * 16 + lr) * EMB + k0 + lg * 8);
        #pragma unroll
        for (int mt = 0; mt < 4; ++mt)
            #pragma unroll
            for (int nt = 0; nt < 4; ++nt)
                acc[mt][nt] = __builtin_amdgcn_mfma_f32_16x16x32_bf16(
                    af[mt], bf[nt], acc[mt][nt], 0, 0, 0);
    }

    float bov[4];
    #pragma unroll
    for (int nt = 0; nt < 4; ++nt) bov[nt] = bo2[n0 + nt * 16 + lr];

    #pragma unroll
    for (int mt = 0; mt < 4; ++mt)
        #pragma unroll
        for (int q = 0; q < 4; ++q) {
            size_t row = m0 + mt * 16 + lg * 4 + q;
            const float* qrow = query + row * EMB;
            float* orow = outp + row * EMB;
            #pragma unroll
            for (int nt = 0; nt < 4; ++nt) {
                int col = n0 + nt * 16 + lr;
                orow[col] = acc[mt][nt][q] + bov[nt] + qrow[col];
            }
        }
}

// ---------------- Kernel 3b: f32 fallback (in-place over d_out, Wcomb f32) -----------
__global__ __launch_bounds__(256) void k3_gemm(
    const float* __restrict__ pre, float* __restrict__ outp,
    const float* __restrict__ query, const float* __restrict__ wcf,
    const float* __restrict__ bo2)
{
    __shared__ float As[64 * EMB];
    int tid = threadIdx.x;
    size_t r0 = (size_t)blockIdx.x * 64;
    {
        const float4* src = (const float4*)(pre + r0 * EMB);
        float4* dst = (float4*)As;
        for (int i = tid; i < 64 * EMB / 4; i += 256) dst[i] = src[i];
    }
    __syncthreads();

    int w = tid >> 6, lane = tid & 63;
    int rb = w * 16;
    float acc[16][4];
    #pragma unroll
    for (int r = 0; r < 16; ++r)
        #pragma unroll
        for (int j = 0; j < 4; ++j) acc[r][j] = 0.f;

    for (int kc = 0; kc < EMB / 4; ++kc) {
        float4 wreg[4];
        #pragma unroll
        for (int j = 0; j < 4; ++j)
            wreg[j] = *(const float4*)&wcf[(size_t)(lane + 64 * j) * EMB + kc * 4];
        #pragma unroll
        for (int r = 0; r < 16; ++r) {
            float4 a = *(const float4*)&As[(rb + r) * EMB + kc * 4];
            #pragma unroll
            for (int j = 0; j < 4; ++j)
                acc[r][j] += a.x * wreg[j].x + a.y * wreg[j].y
                           + a.z * wreg[j].z + a.w * wreg[j].w;
        }
    }

    #pragma unroll
    for (int r = 0; r < 16; ++r) {
        size_t row = r0 + rb + r;
        #pragma unroll
        for (int j = 0; j < 4; ++j) {
            int c = lane + 64 * j;
            outp[row * EMB + c] = acc[r][j] + bo2[c] + query[row * EMB + c];
        }
    }
}

extern "C" void kernel_launch(void* const* d_in, const int* in_sizes, int n_in,
                              void* d_out, int out_size, void* d_ws, size_t ws_size,
                              hipStream_t stream) {
    const float* query = (const float*)d_in[0];
    const float* key   = (const float*)d_in[1];
    const float* value = (const float*)d_in[2];
    const float* refp  = (const float*)d_in[3];
    const float* Wq   = (const float*)d_in[4];
    const float* bq   = (const float*)d_in[5];
    const float* Wk   = (const float*)d_in[6];
    const float* bk   = (const float*)d_in[7];
    const float* Wv   = (const float*)d_in[8];
    const float* bv   = (const float*)d_in[9];
    const float* Woff = (const float*)d_in[10];
    const float* boff = (const float*)d_in[11];
    const float* Wo   = (const float*)d_in[12];
    const float* bo   = (const float*)d_in[13];
    (void)in_sizes; (void)n_in; (void)out_size;

    float* out = (float*)d_out;
    char*  ws  = (char*)d_ws;
    float* kt  = (float*)(ws + KT_OFF);
    float* kb  = (float*)(ws + KB_OFF);
    float* bo2 = (float*)(ws + BO2_OFF);
    float* wcf = (float*)(ws + WCF_OFF);
    __hip_bfloat16* wcb = (__hip_bfloat16*)(ws + WCB_OFF);

    k1_keys<<<BS * NH, 64, 0, stream>>>(query, key, refp, Woff, boff, Wk, bk,
                                        Wq, bq, kt, kb);
    kcomb<<<EMB, 256, 0, stream>>>(Wo, Wv, bv, bo, wcf, wcb, bo2);

    if (ws_size >= WS_FULL) {
        __hip_bfloat16* preb = (__hip_bfloat16*)(ws + PREB_OFF);
        k2_main<1><<<BS * NQ / 4, 256, 0, stream>>>(query, value, refp, Woff, boff,
                                                    kt, kb, nullptr, preb);
        k3_mfma<<<BS * NQ / 64, 256, 0, stream>>>(preb, wcb, out, query, bo2);
    } else {
        k2_main<0><<<BS * NQ / 4, 256, 0, stream>>>(query, value, refp, Woff, boff,
                                                    kt, kb, out, nullptr);
        k3_gemm<<<BS * NQ / 64, 256, 0, stream>>>(out, out, query, wcf, bo2);
    }
}